// Round 16
// baseline (269.417 us; speedup 1.0000x reference)
//
#include <hip/hip_runtime.h>
#include <hip/hip_bf16.h>
#include <stdint.h>

typedef __bf16 bf16_t;
typedef __bf16 bf16x8 __attribute__((ext_vector_type(8)));
typedef __bf16 bf16x4 __attribute__((ext_vector_type(4)));
typedef float f32x4 __attribute__((ext_vector_type(4)));

#define AS1 __attribute__((address_space(1)))
#define AS3 __attribute__((address_space(3)))

static __device__ __forceinline__ void gload_lds16(const void* g, void* l) {
  __builtin_amdgcn_global_load_lds((const AS1 void*)g, (AS3 void*)l, 16, 0, 0);
}

// v_cvt_pk_bf16_f32: dst.lo = bf16(lo), dst.hi = bf16(hi)
static __device__ __forceinline__ uint32_t cvt_pk(float lo, float hi) {
  uint32_t r;
  asm("v_cvt_pk_bf16_f32 %0, %1, %2" : "=v"(r) : "v"(lo), "v"(hi));
  return r;
}

// ---------------- fp32 -> bf16 convert (vectorized x4) ----------------
__global__ void cvt_f32_bf16(const float* __restrict__ in, bf16_t* __restrict__ out, int n4) {
  int i = blockIdx.x * blockDim.x + threadIdx.x;
  if (i >= n4) return;
  float4 v = ((const float4*)in)[i];
  bf16x4 o;
  o[0] = (bf16_t)v.x; o[1] = (bf16_t)v.y; o[2] = (bf16_t)v.z; o[3] = (bf16_t)v.w;
  *(bf16x4*)(out + (size_t)i * 4) = o;
}

// ---------------- GEMM C = A(MxK) * B(NxK)^T, bf16 in, fp32 acc ----------------
// XCD-aware block swizzle (T1). MODE 0: qkv epilogue (q scaled, k row-major,
// v tile-blocked (bh, kt[32], d[64], ksigma[64])). MODE 1: proj (+bias, fp32).
template<int MODE>
__global__ __launch_bounds__(256) void gemm_bt(
    const bf16_t* __restrict__ A, const bf16_t* __restrict__ Bw,
    const float* __restrict__ bias, void* __restrict__ Cout,
    int M, int N, int K)
{
  __shared__ bf16_t As[128 * 32];
  __shared__ bf16_t Bs[128 * 32];
  const int tid = threadIdx.x;
  const int wave = tid >> 6, lane = tid & 63;
  const int l15 = lane & 15, l4 = lane >> 4;
  const int nwgx = gridDim.x;
  const int fid = blockIdx.y * nwgx + blockIdx.x;
  const int qq = (nwgx * gridDim.y) >> 3;
  const int nid = (fid & 7) * qq + (fid >> 3);
  const int m0 = (nid / nwgx) * 128, n0 = (nid % nwgx) * 128;
  const int wm = (wave >> 1) * 64, wn = (wave & 1) * 64;
  f32x4 acc[4][4] = {};

  const int r = tid >> 2;
  const int cb = (tid & 3) * 16;
  const char* gA0 = (const char*)(A + (size_t)(m0 + r) * K) + cb;
  const char* gA1 = (const char*)(A + (size_t)(m0 + 64 + r) * K) + cb;
  const char* gB0 = (const char*)(Bw + (size_t)(n0 + r) * K) + cb;
  const char* gB1 = (const char*)(Bw + (size_t)(n0 + 64 + r) * K) + cb;
  char* lA = (char*)As + tid * 16;
  char* lB = (char*)Bs + tid * 16;

  for (int k0 = 0; k0 < K; k0 += 32) {
    const size_t koff = (size_t)k0 * 2;
    gload_lds16(gA0 + koff, lA);
    gload_lds16(gA1 + koff, lA + 4096);
    gload_lds16(gB0 + koff, lB);
    gload_lds16(gB1 + koff, lB + 4096);
    __syncthreads();
    bf16x8 af[4], bfr[4];
#pragma unroll
    for (int mt = 0; mt < 4; ++mt)
      af[mt] = *(const bf16x8*)&As[(wm + mt * 16 + l15) * 32 + l4 * 8];
#pragma unroll
    for (int nt = 0; nt < 4; ++nt)
      bfr[nt] = *(const bf16x8*)&Bs[(wn + nt * 16 + l15) * 32 + l4 * 8];
#pragma unroll
    for (int mt = 0; mt < 4; ++mt)
#pragma unroll
      for (int nt = 0; nt < 4; ++nt)
        acc[mt][nt] = __builtin_amdgcn_mfma_f32_16x16x32_bf16(af[mt], bfr[nt], acc[mt][nt], 0, 0, 0);
    __syncthreads();
  }

  if (MODE == 0) {
    bf16_t* qkv = (bf16_t*)Cout;
#pragma unroll
    for (int mt = 0; mt < 4; ++mt) {
#pragma unroll
      for (int nt = 0; nt < 4; ++nt) {
        const int col = n0 + wn + nt * 16 + l15;
        const float bv = bias[col];
        const int which = col >> 10;
        const int c = col & 1023;
        const int head = c >> 6, d = c & 63;
#pragma unroll
        for (int i = 0; i < 4; ++i) {
          const int row = m0 + wm + mt * 16 + l4 * 4 + i;
          const int bb = row >> 11, t = row & 2047;
          const int bh2 = bb * 16 + head;
          float v = acc[mt][nt][i] + bv;
          size_t idx;
          if (which == 0) {
            v *= 0.125f;
            idx = ((size_t)(bh2 * 2048 + t) << 6) + d;
          } else if (which == 1) {
            idx = 8388608 + ((size_t)(bh2 * 2048 + t) << 6) + d;
          } else {
            const int ko = t & 63;
            const int pos = (ko & 0x20) | ((ko & 0x0C) << 1) | ((ko & 0x10) >> 2) | (ko & 3);
            idx = 16777216 + (size_t)bh2 * 131072 + ((size_t)(t >> 6) << 12) + d * 64 + pos;
          }
          qkv[idx] = (bf16_t)v;
        }
      }
    }
  } else {
    float* C = (float*)Cout;
#pragma unroll
    for (int mt = 0; mt < 4; ++mt) {
#pragma unroll
      for (int nt = 0; nt < 4; ++nt) {
        const int col = n0 + wn + nt * 16 + l15;
        const float bv = bias[col];
#pragma unroll
        for (int i = 0; i < 4; ++i) {
          const int row = m0 + wm + mt * 16 + l4 * 4 + i;
          C[(size_t)row * N + col] = acc[mt][nt][i] + bv;
        }
      }
    }
  }
}

// ---------------- one 16-q-row half-step (swapped-operand, in-lane SM) ----
static __device__ __forceinline__ void half_step(
    const bf16x8& kA0, const bf16x8& kB0, const bf16x8& kA1, const bf16x8& kB1,
    const bf16x8& kA2, const bf16x8& kB2, const bf16x8& kA3, const bf16x8& kB3,
    const bf16x8& vA0, const bf16x8& vB0, const bf16x8& vA1, const bf16x8& vB1,
    const bf16x8& vA2, const bf16x8& vB2, const bf16x8& vA3, const bf16x8& vB3,
    const bf16x8 aq0, const bf16x8 aq1,
    float& m_i, float& l_i,
    f32x4& o0, f32x4& o1, f32x4& o2, f32x4& o3,
    const bool diag, const int qb, const int kb)
{
  f32x4 s0 = {}, s1 = {}, s2 = {}, s3 = {};
  s0 = __builtin_amdgcn_mfma_f32_16x16x32_bf16(kA0, aq0, s0, 0, 0, 0);
  s0 = __builtin_amdgcn_mfma_f32_16x16x32_bf16(kB0, aq1, s0, 0, 0, 0);
  s1 = __builtin_amdgcn_mfma_f32_16x16x32_bf16(kA1, aq0, s1, 0, 0, 0);
  s1 = __builtin_amdgcn_mfma_f32_16x16x32_bf16(kB1, aq1, s1, 0, 0, 0);
  s2 = __builtin_amdgcn_mfma_f32_16x16x32_bf16(kA2, aq0, s2, 0, 0, 0);
  s2 = __builtin_amdgcn_mfma_f32_16x16x32_bf16(kB2, aq1, s2, 0, 0, 0);
  s3 = __builtin_amdgcn_mfma_f32_16x16x32_bf16(kA3, aq0, s3, 0, 0, 0);
  s3 = __builtin_amdgcn_mfma_f32_16x16x32_bf16(kB3, aq1, s3, 0, 0, 0);

  if (diag) {
#pragma unroll
    for (int i = 0; i < 4; ++i) {
      if (kb + i > qb)      s0[i] = -1e30f;
      if (16 + kb + i > qb) s1[i] = -1e30f;
      if (32 + kb + i > qb) s2[i] = -1e30f;
      if (48 + kb + i > qb) s3[i] = -1e30f;
    }
  }

  float pm = fmaxf(fmaxf(fmaxf(s0[0], s0[1]), fmaxf(s0[2], s0[3])),
                   fmaxf(fmaxf(s1[0], s1[1]), fmaxf(s1[2], s1[3])));
  pm = fmaxf(pm, fmaxf(fmaxf(fmaxf(s2[0], s2[1]), fmaxf(s2[2], s2[3])),
                       fmaxf(fmaxf(s3[0], s3[1]), fmaxf(s3[2], s3[3]))));
  pm = fmaxf(pm, __shfl_xor(pm, 16));
  pm = fmaxf(pm, __shfl_xor(pm, 32));

  // defer-max: skip rescale when the running max barely grows (P <= e^8)
  const bool keep = __all(pm - m_i <= 8.f);
  const float mn = keep ? m_i : fmaxf(m_i, pm);
  const float sc = keep ? 1.f : __expf(m_i - mn);
  m_i = mn;
#pragma unroll
  for (int i = 0; i < 4; ++i) {
    s0[i] = __expf(s0[i] - mn);
    s1[i] = __expf(s1[i] - mn);
    s2[i] = __expf(s2[i] - mn);
    s3[i] = __expf(s3[i] - mn);
  }
  float rs = ((s0[0] + s0[1]) + (s0[2] + s0[3])) + ((s1[0] + s1[1]) + (s1[2] + s1[3]))
           + ((s2[0] + s2[1]) + (s2[2] + s2[3])) + ((s3[0] + s3[1]) + (s3[2] + s3[3]));
  rs += __shfl_xor(rs, 16);
  rs += __shfl_xor(rs, 32);
  if (keep) {
    l_i = l_i + rs;
  } else {
    l_i = l_i * sc + rs;
    o0 *= sc; o1 *= sc; o2 *= sc; o3 *= sc;
  }

  union { uint32_t u[4]; bf16x8 v; } B0, B1;
  B0.u[0] = cvt_pk(s0[0], s0[1]); B0.u[1] = cvt_pk(s0[2], s0[3]);
  B0.u[2] = cvt_pk(s1[0], s1[1]); B0.u[3] = cvt_pk(s1[2], s1[3]);
  B1.u[0] = cvt_pk(s2[0], s2[1]); B1.u[1] = cvt_pk(s2[2], s2[3]);
  B1.u[2] = cvt_pk(s3[0], s3[1]); B1.u[3] = cvt_pk(s3[2], s3[3]);

  o0 = __builtin_amdgcn_mfma_f32_16x16x32_bf16(vA0, B0.v, o0, 0, 0, 0);
  o0 = __builtin_amdgcn_mfma_f32_16x16x32_bf16(vB0, B1.v, o0, 0, 0, 0);
  o1 = __builtin_amdgcn_mfma_f32_16x16x32_bf16(vA1, B0.v, o1, 0, 0, 0);
  o1 = __builtin_amdgcn_mfma_f32_16x16x32_bf16(vB1, B1.v, o1, 0, 0, 0);
  o2 = __builtin_amdgcn_mfma_f32_16x16x32_bf16(vA2, B0.v, o2, 0, 0, 0);
  o2 = __builtin_amdgcn_mfma_f32_16x16x32_bf16(vB2, B1.v, o2, 0, 0, 0);
  o3 = __builtin_amdgcn_mfma_f32_16x16x32_bf16(vA3, B0.v, o3, 0, 0, 0);
  o3 = __builtin_amdgcn_mfma_f32_16x16x32_bf16(vB3, B1.v, o3, 0, 0, 0);
}

// ---------------- causal flash attention: split-K x4 per q-group ---------
// grid 4096 x 256. Block = one (bh, 32-row q-group); wave w handles
// kt = w, w+4, ... <= bound (stride-4 split-K; online softmax valid on any
// k-subset; the wave owning kt==bound applies the diagonal mask). LDS merge:
// waves post (m,l) per row, everyone computes m*, l*, scales own O; waves
// 1..3 write O to XOR-swizzled LDS; wave 0 accumulates + epilogue.
// Cuts the serial chain 33 -> <=9 trips and creates a backfill queue
// (16384 waves >> resident) -> sustained occupancy, no drain tail.
__global__ __launch_bounds__(256) void flash_attn(
    const bf16_t* __restrict__ Qg, const bf16_t* __restrict__ Kg,
    const bf16_t* __restrict__ VTg, bf16_t* __restrict__ Y)
{
  const int T = 2048, HS = 64;
  const int flat = blockIdx.x;         // 0..4095
  const int xcd = flat & 7;
  const int rest = flat >> 3;          // 0..511
  const int bh = xcd * 8 + (rest & 7); // 8 heads per XCD -> K/V L2-resident
  const int s = 63 - (rest >> 3);      // 32-row q-group, longest first
  const int wave = threadIdx.x >> 6;   // k-chunk of this wave
  const size_t baseQ = (size_t)bh * T * HS;   // Q,K: (bh, t, d)
  const size_t baseV = (size_t)bh * HS * T;   // V: (bh, kt, d, ksigma) tiles

  __shared__ float mlbuf[4][2][16][2];
  __shared__ char obuf[3 * 8192];

  const int lane = threadIdx.x & 63;
  const int l15 = lane & 15, l4 = lane >> 4;

  const int bound = s >> 1;                 // last k-tile (same for halves)
  const int qb0 = ((s & 1) << 5) + l15;     // q offset within diag 64-tile
  const int qb1 = qb0 + 16;
  const int kb = l4 * 4;

  // Q fragments: half0 rows 32s+l15, half1 rows 32s+16+l15
  const bf16_t* qr = Qg + baseQ + (size_t)(32 * s + l15) * HS;
  const bf16x8 aq00 = *(const bf16x8*)(qr + l4 * 8);
  const bf16x8 aq01 = *(const bf16x8*)(qr + 32 + l4 * 8);
  const bf16x8 aq10 = *(const bf16x8*)(qr + 16 * HS + l4 * 8);
  const bf16x8 aq11 = *(const bf16x8*)(qr + 16 * HS + 32 + l4 * 8);

  float m0 = -1e30f, l0 = 0.f, m1 = -1e30f, l1 = 0.f;
  f32x4 o00 = {}, o01 = {}, o02 = {}, o03 = {};
  f32x4 o10 = {}, o11 = {}, o12 = {}, o13 = {};

  // per-lane fragment bases, offset to this wave's first k-tile
  const bf16_t* kp = Kg + baseQ + (size_t)l15 * HS + l4 * 8 + (size_t)wave * 4096;
  const bf16_t* vp = VTg + baseV + (size_t)l15 * 64 + l4 * 8 + (size_t)wave * 4096;

  for (int kt = wave; kt <= bound; kt += 4) {
    const bool dg = (kt == bound);
    const bf16x8 kA0 = *(const bf16x8*)(kp + 0);
    const bf16x8 kB0 = *(const bf16x8*)(kp + 32);
    const bf16x8 kA1 = *(const bf16x8*)(kp + 1024);
    const bf16x8 kB1 = *(const bf16x8*)(kp + 1024 + 32);
    const bf16x8 kA2 = *(const bf16x8*)(kp + 2048);
    const bf16x8 kB2 = *(const bf16x8*)(kp + 2048 + 32);
    const bf16x8 kA3 = *(const bf16x8*)(kp + 3072);
    const bf16x8 kB3 = *(const bf16x8*)(kp + 3072 + 32);
    const bf16x8 vA0 = *(const bf16x8*)(vp + 0);
    const bf16x8 vB0 = *(const bf16x8*)(vp + 32);
    const bf16x8 vA1 = *(const bf16x8*)(vp + 1024);
    const bf16x8 vB1 = *(const bf16x8*)(vp + 1024 + 32);
    const bf16x8 vA2 = *(const bf16x8*)(vp + 2048);
    const bf16x8 vB2 = *(const bf16x8*)(vp + 2048 + 32);
    const bf16x8 vA3 = *(const bf16x8*)(vp + 3072);
    const bf16x8 vB3 = *(const bf16x8*)(vp + 3072 + 32);

    half_step(kA0, kB0, kA1, kB1, kA2, kB2, kA3, kB3,
              vA0, vB0, vA1, vB1, vA2, vB2, vA3, vB3,
              aq00, aq01, m0, l0, o00, o01, o02, o03, dg, qb0, kb);
    half_step(kA0, kB0, kA1, kB1, kA2, kB2, kA3, kB3,
              vA0, vB0, vA1, vB1, vA2, vB2, vA3, vB3,
              aq10, aq11, m1, l1, o10, o11, o12, o13, dg, qb1, kb);

    kp += 16384;   // 4 k-tiles ahead
    vp += 16384;
  }

  // ---- split-K merge ----
  if (l4 == 0) {
    mlbuf[wave][0][l15][0] = m0; mlbuf[wave][0][l15][1] = l0;
    mlbuf[wave][1][l15][0] = m1; mlbuf[wave][1][l15][1] = l1;
  }
  __syncthreads();
  const float ms0 = fmaxf(fmaxf(mlbuf[0][0][l15][0], mlbuf[1][0][l15][0]),
                          fmaxf(mlbuf[2][0][l15][0], mlbuf[3][0][l15][0]));
  const float ms1 = fmaxf(fmaxf(mlbuf[0][1][l15][0], mlbuf[1][1][l15][0]),
                          fmaxf(mlbuf[2][1][l15][0], mlbuf[3][1][l15][0]));
  float ls0 = 0.f, ls1 = 0.f;
#pragma unroll
  for (int w = 0; w < 4; ++w) {
    ls0 += mlbuf[w][0][l15][1] * __expf(mlbuf[w][0][l15][0] - ms0);
    ls1 += mlbuf[w][1][l15][1] * __expf(mlbuf[w][1][l15][0] - ms1);
  }
  const float sc0 = __expf(m0 - ms0);
  const float sc1 = __expf(m1 - ms1);
  o00 *= sc0; o01 *= sc0; o02 *= sc0; o03 *= sc0;
  o10 *= sc1; o11 *= sc1; o12 *= sc1; o13 *= sc1;

  const int lsw = lane & 7;  // XOR swizzle keeps b128 conflict-free
  if (wave != 0) {
    char* dst = obuf + (wave - 1) * 8192 + lane * 128;
    *(f32x4*)(dst + ((0 ^ lsw) << 4)) = o00;
    *(f32x4*)(dst + ((1 ^ lsw) << 4)) = o01;
    *(f32x4*)(dst + ((2 ^ lsw) << 4)) = o02;
    *(f32x4*)(dst + ((3 ^ lsw) << 4)) = o03;
    *(f32x4*)(dst + ((4 ^ lsw) << 4)) = o10;
    *(f32x4*)(dst + ((5 ^ lsw) << 4)) = o11;
    *(f32x4*)(dst + ((6 ^ lsw) << 4)) = o12;
    *(f32x4*)(dst + ((7 ^ lsw) << 4)) = o13;
  }
  __syncthreads();
  if (wave == 0) {
#pragma unroll
    for (int p = 0; p < 3; ++p) {
      const char* src = obuf + p * 8192 + lane * 128;
      o00 += *(const f32x4*)(src + ((0 ^ lsw) << 4));
      o01 += *(const f32x4*)(src + ((1 ^ lsw) << 4));
      o02 += *(const f32x4*)(src + ((2 ^ lsw) << 4));
      o03 += *(const f32x4*)(src + ((3 ^ lsw) << 4));
      o10 += *(const f32x4*)(src + ((4 ^ lsw) << 4));
      o11 += *(const f32x4*)(src + ((5 ^ lsw) << 4));
      o12 += *(const f32x4*)(src + ((6 ^ lsw) << 4));
      o13 += *(const f32x4*)(src + ((7 ^ lsw) << 4));
    }
    // epilogue: O^T (d = t*16+l4*4+i, q = l15) -> Y (B,T,C) bf16, 8B packed
    const int b = bh >> 4, h = bh & 15;
    {
      const float il = 1.f / ls0;
      const int q = 32 * s + l15;
      bf16_t* yr = Y + ((size_t)(b * T + q)) * 1024 + h * 64 + l4 * 4;
      uint2 w;
      w.x = cvt_pk(o00[0] * il, o00[1] * il); w.y = cvt_pk(o00[2] * il, o00[3] * il);
      *(uint2*)(yr + 0) = w;
      w.x = cvt_pk(o01[0] * il, o01[1] * il); w.y = cvt_pk(o01[2] * il, o01[3] * il);
      *(uint2*)(yr + 16) = w;
      w.x = cvt_pk(o02[0] * il, o02[1] * il); w.y = cvt_pk(o02[2] * il, o02[3] * il);
      *(uint2*)(yr + 32) = w;
      w.x = cvt_pk(o03[0] * il, o03[1] * il); w.y = cvt_pk(o03[2] * il, o03[3] * il);
      *(uint2*)(yr + 48) = w;
    }
    {
      const float il = 1.f / ls1;
      const int q = 32 * s + 16 + l15;
      bf16_t* yr = Y + ((size_t)(b * T + q)) * 1024 + h * 64 + l4 * 4;
      uint2 w;
      w.x = cvt_pk(o10[0] * il, o10[1] * il); w.y = cvt_pk(o10[2] * il, o10[3] * il);
      *(uint2*)(yr + 0) = w;
      w.x = cvt_pk(o11[0] * il, o11[1] * il); w.y = cvt_pk(o11[2] * il, o11[3] * il);
      *(uint2*)(yr + 16) = w;
      w.x = cvt_pk(o12[0] * il, o12[1] * il); w.y = cvt_pk(o12[2] * il, o12[3] * il);
      *(uint2*)(yr + 32) = w;
      w.x = cvt_pk(o13[0] * il, o13[1] * il); w.y = cvt_pk(o13[2] * il, o13[3] * il);
      *(uint2*)(yr + 48) = w;
    }
  }
}

// ---------------- launch ----------------
extern "C" void kernel_launch(void* const* d_in, const int* in_sizes, int n_in,
                              void* d_out, int out_size, void* d_ws, size_t ws_size,
                              hipStream_t stream) {
  const float* x      = (const float*)d_in[0];
  const float* w_attn = (const float*)d_in[1];
  const float* b_attn = (const float*)d_in[2];
  const float* w_proj = (const float*)d_in[3];
  const float* b_proj = (const float*)d_in[4];
  float* out = (float*)d_out;

  char* ws = (char*)d_ws;
  bf16_t* xb   = (bf16_t*)(ws);
  bf16_t* wab  = (bf16_t*)(ws + 16777216);
  bf16_t* wpb  = (bf16_t*)(ws + 23068672);
  bf16_t* qkvb = (bf16_t*)(ws + 25165824);   // q | k | vTiles (8M elems each)
  bf16_t* yb   = (bf16_t*)(ws + 75497472);

  cvt_f32_bf16<<<8192, 256, 0, stream>>>(x, xb, 2097152);
  cvt_f32_bf16<<<3072, 256, 0, stream>>>(w_attn, wab, 786432);
  cvt_f32_bf16<<<1024, 256, 0, stream>>>(w_proj, wpb, 262144);

  dim3 g1(24, 64);
  gemm_bt<0><<<g1, 256, 0, stream>>>(xb, wab, b_attn, (void*)qkvb, 8192, 3072, 1024);

  flash_attn<<<4096, 256, 0, stream>>>(qkvb, qkvb + 8388608, qkvb + 16777216, yb);

  dim3 g3(8, 64);
  gemm_bt<1><<<g3, 256, 0, stream>>>(yb, wpb, b_proj, (void*)out, 8192, 1024, 1024);
}

// Round 17
// 224.496 us; speedup vs baseline: 1.2001x; 1.2001x over previous
//
#include <hip/hip_runtime.h>
#include <hip/hip_bf16.h>
#include <stdint.h>

typedef __bf16 bf16_t;
typedef __bf16 bf16x8 __attribute__((ext_vector_type(8)));
typedef __bf16 bf16x4 __attribute__((ext_vector_type(4)));
typedef float f32x4 __attribute__((ext_vector_type(4)));

#define AS1 __attribute__((address_space(1)))
#define AS3 __attribute__((address_space(3)))

static __device__ __forceinline__ void gload_lds16(const void* g, void* l) {
  __builtin_amdgcn_global_load_lds((const AS1 void*)g, (AS3 void*)l, 16, 0, 0);
}

// v_cvt_pk_bf16_f32: dst.lo = bf16(lo), dst.hi = bf16(hi)
static __device__ __forceinline__ uint32_t cvt_pk(float lo, float hi) {
  uint32_t r;
  asm("v_cvt_pk_bf16_f32 %0, %1, %2" : "=v"(r) : "v"(lo), "v"(hi));
  return r;
}

// ---------------- fp32 -> bf16 convert (vectorized x4) ----------------
__global__ void cvt_f32_bf16(const float* __restrict__ in, bf16_t* __restrict__ out, int n4) {
  int i = blockIdx.x * blockDim.x + threadIdx.x;
  if (i >= n4) return;
  float4 v = ((const float4*)in)[i];
  bf16x4 o;
  o[0] = (bf16_t)v.x; o[1] = (bf16_t)v.y; o[2] = (bf16_t)v.z; o[3] = (bf16_t)v.w;
  *(bf16x4*)(out + (size_t)i * 4) = o;
}

// ---------------- GEMM C = A(MxK) * B(NxK)^T, bf16 in, fp32 acc ----------------
// XCD-aware block swizzle (T1). MODE 0: qkv epilogue (q scaled, k row-major,
// v tile-blocked (bh, kt[32], d[64], ksigma[64])). MODE 1: proj (+bias, fp32).
template<int MODE>
__global__ __launch_bounds__(256) void gemm_bt(
    const bf16_t* __restrict__ A, const bf16_t* __restrict__ Bw,
    const float* __restrict__ bias, void* __restrict__ Cout,
    int M, int N, int K)
{
  __shared__ bf16_t As[128 * 32];
  __shared__ bf16_t Bs[128 * 32];
  const int tid = threadIdx.x;
  const int wave = tid >> 6, lane = tid & 63;
  const int l15 = lane & 15, l4 = lane >> 4;
  const int nwgx = gridDim.x;
  const int fid = blockIdx.y * nwgx + blockIdx.x;
  const int qq = (nwgx * gridDim.y) >> 3;
  const int nid = (fid & 7) * qq + (fid >> 3);
  const int m0 = (nid / nwgx) * 128, n0 = (nid % nwgx) * 128;
  const int wm = (wave >> 1) * 64, wn = (wave & 1) * 64;
  f32x4 acc[4][4] = {};

  const int r = tid >> 2;
  const int cb = (tid & 3) * 16;
  const char* gA0 = (const char*)(A + (size_t)(m0 + r) * K) + cb;
  const char* gA1 = (const char*)(A + (size_t)(m0 + 64 + r) * K) + cb;
  const char* gB0 = (const char*)(Bw + (size_t)(n0 + r) * K) + cb;
  const char* gB1 = (const char*)(Bw + (size_t)(n0 + 64 + r) * K) + cb;
  char* lA = (char*)As + tid * 16;
  char* lB = (char*)Bs + tid * 16;

  for (int k0 = 0; k0 < K; k0 += 32) {
    const size_t koff = (size_t)k0 * 2;
    gload_lds16(gA0 + koff, lA);
    gload_lds16(gA1 + koff, lA + 4096);
    gload_lds16(gB0 + koff, lB);
    gload_lds16(gB1 + koff, lB + 4096);
    __syncthreads();
    bf16x8 af[4], bfr[4];
#pragma unroll
    for (int mt = 0; mt < 4; ++mt)
      af[mt] = *(const bf16x8*)&As[(wm + mt * 16 + l15) * 32 + l4 * 8];
#pragma unroll
    for (int nt = 0; nt < 4; ++nt)
      bfr[nt] = *(const bf16x8*)&Bs[(wn + nt * 16 + l15) * 32 + l4 * 8];
#pragma unroll
    for (int mt = 0; mt < 4; ++mt)
#pragma unroll
      for (int nt = 0; nt < 4; ++nt)
        acc[mt][nt] = __builtin_amdgcn_mfma_f32_16x16x32_bf16(af[mt], bfr[nt], acc[mt][nt], 0, 0, 0);
    __syncthreads();
  }

  if (MODE == 0) {
    bf16_t* qkv = (bf16_t*)Cout;
#pragma unroll
    for (int mt = 0; mt < 4; ++mt) {
#pragma unroll
      for (int nt = 0; nt < 4; ++nt) {
        const int col = n0 + wn + nt * 16 + l15;
        const float bv = bias[col];
        const int which = col >> 10;
        const int c = col & 1023;
        const int head = c >> 6, d = c & 63;
#pragma unroll
        for (int i = 0; i < 4; ++i) {
          const int row = m0 + wm + mt * 16 + l4 * 4 + i;
          const int bb = row >> 11, t = row & 2047;
          const int bh2 = bb * 16 + head;
          float v = acc[mt][nt][i] + bv;
          size_t idx;
          if (which == 0) {
            v *= 0.125f;
            idx = ((size_t)(bh2 * 2048 + t) << 6) + d;
          } else if (which == 1) {
            idx = 8388608 + ((size_t)(bh2 * 2048 + t) << 6) + d;
          } else {
            const int ko = t & 63;
            const int pos = (ko & 0x20) | ((ko & 0x0C) << 1) | ((ko & 0x10) >> 2) | (ko & 3);
            idx = 16777216 + (size_t)bh2 * 131072 + ((size_t)(t >> 6) << 12) + d * 64 + pos;
          }
          qkv[idx] = (bf16_t)v;
        }
      }
    }
  } else {
    float* C = (float*)Cout;
#pragma unroll
    for (int mt = 0; mt < 4; ++mt) {
#pragma unroll
      for (int nt = 0; nt < 4; ++nt) {
        const int col = n0 + wn + nt * 16 + l15;
        const float bv = bias[col];
#pragma unroll
        for (int i = 0; i < 4; ++i) {
          const int row = m0 + wm + mt * 16 + l4 * 4 + i;
          C[(size_t)row * N + col] = acc[mt][nt][i] + bv;
        }
      }
    }
  }
}

// ---------------- one 16-q-row half-step (swapped-operand, in-lane SM) ----
static __device__ __forceinline__ void half_step(
    const bf16x8& kA0, const bf16x8& kB0, const bf16x8& kA1, const bf16x8& kB1,
    const bf16x8& kA2, const bf16x8& kB2, const bf16x8& kA3, const bf16x8& kB3,
    const bf16x8& vA0, const bf16x8& vB0, const bf16x8& vA1, const bf16x8& vB1,
    const bf16x8& vA2, const bf16x8& vB2, const bf16x8& vA3, const bf16x8& vB3,
    const bf16x8 aq0, const bf16x8 aq1,
    float& m_i, float& l_i,
    f32x4& o0, f32x4& o1, f32x4& o2, f32x4& o3,
    const bool diag, const int qb, const int kb)
{
  f32x4 s0 = {}, s1 = {}, s2 = {}, s3 = {};
  s0 = __builtin_amdgcn_mfma_f32_16x16x32_bf16(kA0, aq0, s0, 0, 0, 0);
  s0 = __builtin_amdgcn_mfma_f32_16x16x32_bf16(kB0, aq1, s0, 0, 0, 0);
  s1 = __builtin_amdgcn_mfma_f32_16x16x32_bf16(kA1, aq0, s1, 0, 0, 0);
  s1 = __builtin_amdgcn_mfma_f32_16x16x32_bf16(kB1, aq1, s1, 0, 0, 0);
  s2 = __builtin_amdgcn_mfma_f32_16x16x32_bf16(kA2, aq0, s2, 0, 0, 0);
  s2 = __builtin_amdgcn_mfma_f32_16x16x32_bf16(kB2, aq1, s2, 0, 0, 0);
  s3 = __builtin_amdgcn_mfma_f32_16x16x32_bf16(kA3, aq0, s3, 0, 0, 0);
  s3 = __builtin_amdgcn_mfma_f32_16x16x32_bf16(kB3, aq1, s3, 0, 0, 0);

  if (diag) {
#pragma unroll
    for (int i = 0; i < 4; ++i) {
      if (kb + i > qb)      s0[i] = -1e30f;
      if (16 + kb + i > qb) s1[i] = -1e30f;
      if (32 + kb + i > qb) s2[i] = -1e30f;
      if (48 + kb + i > qb) s3[i] = -1e30f;
    }
  }

  float pm = fmaxf(fmaxf(fmaxf(s0[0], s0[1]), fmaxf(s0[2], s0[3])),
                   fmaxf(fmaxf(s1[0], s1[1]), fmaxf(s1[2], s1[3])));
  pm = fmaxf(pm, fmaxf(fmaxf(fmaxf(s2[0], s2[1]), fmaxf(s2[2], s2[3])),
                       fmaxf(fmaxf(s3[0], s3[1]), fmaxf(s3[2], s3[3]))));
  pm = fmaxf(pm, __shfl_xor(pm, 16));
  pm = fmaxf(pm, __shfl_xor(pm, 32));

  // defer-max: skip rescale when the running max barely grows (P <= e^8)
  const bool keep = __all(pm - m_i <= 8.f);
  const float mn = keep ? m_i : fmaxf(m_i, pm);
  const float sc = keep ? 1.f : __expf(m_i - mn);
  m_i = mn;
#pragma unroll
  for (int i = 0; i < 4; ++i) {
    s0[i] = __expf(s0[i] - mn);
    s1[i] = __expf(s1[i] - mn);
    s2[i] = __expf(s2[i] - mn);
    s3[i] = __expf(s3[i] - mn);
  }
  float rs = ((s0[0] + s0[1]) + (s0[2] + s0[3])) + ((s1[0] + s1[1]) + (s1[2] + s1[3]))
           + ((s2[0] + s2[1]) + (s2[2] + s2[3])) + ((s3[0] + s3[1]) + (s3[2] + s3[3]));
  rs += __shfl_xor(rs, 16);
  rs += __shfl_xor(rs, 32);
  if (keep) {
    l_i = l_i + rs;
  } else {
    l_i = l_i * sc + rs;
    o0 *= sc; o1 *= sc; o2 *= sc; o3 *= sc;
  }

  union { uint32_t u[4]; bf16x8 v; } B0, B1;
  B0.u[0] = cvt_pk(s0[0], s0[1]); B0.u[1] = cvt_pk(s0[2], s0[3]);
  B0.u[2] = cvt_pk(s1[0], s1[1]); B0.u[3] = cvt_pk(s1[2], s1[3]);
  B1.u[0] = cvt_pk(s2[0], s2[1]); B1.u[1] = cvt_pk(s2[2], s2[3]);
  B1.u[2] = cvt_pk(s3[0], s3[1]); B1.u[3] = cvt_pk(s3[2], s3[3]);

  o0 = __builtin_amdgcn_mfma_f32_16x16x32_bf16(vA0, B0.v, o0, 0, 0, 0);
  o0 = __builtin_amdgcn_mfma_f32_16x16x32_bf16(vB0, B1.v, o0, 0, 0, 0);
  o1 = __builtin_amdgcn_mfma_f32_16x16x32_bf16(vA1, B0.v, o1, 0, 0, 0);
  o1 = __builtin_amdgcn_mfma_f32_16x16x32_bf16(vB1, B1.v, o1, 0, 0, 0);
  o2 = __builtin_amdgcn_mfma_f32_16x16x32_bf16(vA2, B0.v, o2, 0, 0, 0);
  o2 = __builtin_amdgcn_mfma_f32_16x16x32_bf16(vB2, B1.v, o2, 0, 0, 0);
  o3 = __builtin_amdgcn_mfma_f32_16x16x32_bf16(vA3, B0.v, o3, 0, 0, 0);
  o3 = __builtin_amdgcn_mfma_f32_16x16x32_bf16(vB3, B1.v, o3, 0, 0, 0);
}

// ---------------- causal flash attention: 64 q-rows / wave ---------------
// grid 2048 x 64 threads. Wave owns q-rows [64s, 64s+64) as FOUR 16-row
// halves sharing ONE K set + ONE V set per k-tile. Halves all have
// bound = s (64-row group spans exactly one 64-k tile); diag masks differ
// only by qb = 16h + l15. Halves the L2 line-request count per unit of
// attention work (the measured chip-wide wall: ~520 trips/us in every
// 32-row variant R7-R16). No prefetch sets (R14's VGPR blowup suspect);
// single K/V sets keep peak ~190 VGPR. No LDS, no barriers.
__global__ __launch_bounds__(64) void flash_attn(
    const bf16_t* __restrict__ Qg, const bf16_t* __restrict__ Kg,
    const bf16_t* __restrict__ VTg, bf16_t* __restrict__ Y)
{
  const int T = 2048, HS = 64;
  const int flat = blockIdx.x;         // 0..2047
  const int xcd = flat & 7;
  const int rest = flat >> 3;          // 0..255
  const int bh = xcd * 8 + (rest & 7); // 8 heads per XCD -> K/V L2-resident
  const int s = 31 - (rest >> 3);      // 64-row q-group, longest first
  const size_t baseQ = (size_t)bh * T * HS;   // Q,K: (bh, t, d)
  const size_t baseV = (size_t)bh * HS * T;   // V: (bh, kt, d, ksigma) tiles

  const int lane = threadIdx.x & 63;
  const int l15 = lane & 15, l4 = lane >> 4;

  const int bound = s;                 // last k-tile, same for all 4 halves
  const int kb = l4 * 4;
  const int qb0 = l15;                 // q offsets within the diag 64-tile
  const int qb1 = l15 + 16;
  const int qb2 = l15 + 32;
  const int qb3 = l15 + 48;

  // Q fragments: half h rows 64s + 16h + l15
  const bf16_t* qr = Qg + baseQ + (size_t)(64 * s + l15) * HS;
  const bf16x8 aq00 = *(const bf16x8*)(qr + l4 * 8);
  const bf16x8 aq01 = *(const bf16x8*)(qr + 32 + l4 * 8);
  const bf16x8 aq10 = *(const bf16x8*)(qr + 16 * HS + l4 * 8);
  const bf16x8 aq11 = *(const bf16x8*)(qr + 16 * HS + 32 + l4 * 8);
  const bf16x8 aq20 = *(const bf16x8*)(qr + 32 * HS + l4 * 8);
  const bf16x8 aq21 = *(const bf16x8*)(qr + 32 * HS + 32 + l4 * 8);
  const bf16x8 aq30 = *(const bf16x8*)(qr + 48 * HS + l4 * 8);
  const bf16x8 aq31 = *(const bf16x8*)(qr + 48 * HS + 32 + l4 * 8);

  float m0 = -1e30f, l0 = 0.f, m1 = -1e30f, l1 = 0.f;
  float m2 = -1e30f, l2 = 0.f, m3 = -1e30f, l3 = 0.f;
  f32x4 o00 = {}, o01 = {}, o02 = {}, o03 = {};
  f32x4 o10 = {}, o11 = {}, o12 = {}, o13 = {};
  f32x4 o20 = {}, o21 = {}, o22 = {}, o23 = {};
  f32x4 o30 = {}, o31 = {}, o32 = {}, o33 = {};

  // per-lane fragment bases (both advance 4096 elems per k-tile)
  const bf16_t* kp = Kg + baseQ + (size_t)l15 * HS + l4 * 8;
  const bf16_t* vp = VTg + baseV + (size_t)l15 * 64 + l4 * 8;

  for (int kt = 0; kt <= bound; ++kt) {
    const bool dg = (kt == bound);
    const bf16x8 kA0 = *(const bf16x8*)(kp + 0);
    const bf16x8 kB0 = *(const bf16x8*)(kp + 32);
    const bf16x8 kA1 = *(const bf16x8*)(kp + 1024);
    const bf16x8 kB1 = *(const bf16x8*)(kp + 1024 + 32);
    const bf16x8 kA2 = *(const bf16x8*)(kp + 2048);
    const bf16x8 kB2 = *(const bf16x8*)(kp + 2048 + 32);
    const bf16x8 kA3 = *(const bf16x8*)(kp + 3072);
    const bf16x8 kB3 = *(const bf16x8*)(kp + 3072 + 32);
    const bf16x8 vA0 = *(const bf16x8*)(vp + 0);
    const bf16x8 vB0 = *(const bf16x8*)(vp + 32);
    const bf16x8 vA1 = *(const bf16x8*)(vp + 1024);
    const bf16x8 vB1 = *(const bf16x8*)(vp + 1024 + 32);
    const bf16x8 vA2 = *(const bf16x8*)(vp + 2048);
    const bf16x8 vB2 = *(const bf16x8*)(vp + 2048 + 32);
    const bf16x8 vA3 = *(const bf16x8*)(vp + 3072);
    const bf16x8 vB3 = *(const bf16x8*)(vp + 3072 + 32);

    half_step(kA0, kB0, kA1, kB1, kA2, kB2, kA3, kB3,
              vA0, vB0, vA1, vB1, vA2, vB2, vA3, vB3,
              aq00, aq01, m0, l0, o00, o01, o02, o03, dg, qb0, kb);
    half_step(kA0, kB0, kA1, kB1, kA2, kB2, kA3, kB3,
              vA0, vB0, vA1, vB1, vA2, vB2, vA3, vB3,
              aq10, aq11, m1, l1, o10, o11, o12, o13, dg, qb1, kb);
    half_step(kA0, kB0, kA1, kB1, kA2, kB2, kA3, kB3,
              vA0, vB0, vA1, vB1, vA2, vB2, vA3, vB3,
              aq20, aq21, m2, l2, o20, o21, o22, o23, dg, qb2, kb);
    half_step(kA0, kB0, kA1, kB1, kA2, kB2, kA3, kB3,
              vA0, vB0, vA1, vB1, vA2, vB2, vA3, vB3,
              aq30, aq31, m3, l3, o30, o31, o32, o33, dg, qb3, kb);

    kp += 4096;
    vp += 4096;
  }

  // epilogue: O^T (d = t*16+l4*4+i, q = l15) -> Y (B,T,C) bf16, packed 8B
  const int b = bh >> 4, h = bh & 15;
  {
    const float il = 1.f / l0;
    const int q = 64 * s + l15;
    bf16_t* yr = Y + ((size_t)(b * T + q)) * 1024 + h * 64 + l4 * 4;
    uint2 w;
    w.x = cvt_pk(o00[0] * il, o00[1] * il); w.y = cvt_pk(o00[2] * il, o00[3] * il);
    *(uint2*)(yr + 0) = w;
    w.x = cvt_pk(o01[0] * il, o01[1] * il); w.y = cvt_pk(o01[2] * il, o01[3] * il);
    *(uint2*)(yr + 16) = w;
    w.x = cvt_pk(o02[0] * il, o02[1] * il); w.y = cvt_pk(o02[2] * il, o02[3] * il);
    *(uint2*)(yr + 32) = w;
    w.x = cvt_pk(o03[0] * il, o03[1] * il); w.y = cvt_pk(o03[2] * il, o03[3] * il);
    *(uint2*)(yr + 48) = w;
  }
  {
    const float il = 1.f / l1;
    const int q = 64 * s + 16 + l15;
    bf16_t* yr = Y + ((size_t)(b * T + q)) * 1024 + h * 64 + l4 * 4;
    uint2 w;
    w.x = cvt_pk(o10[0] * il, o10[1] * il); w.y = cvt_pk(o10[2] * il, o10[3] * il);
    *(uint2*)(yr + 0) = w;
    w.x = cvt_pk(o11[0] * il, o11[1] * il); w.y = cvt_pk(o11[2] * il, o11[3] * il);
    *(uint2*)(yr + 16) = w;
    w.x = cvt_pk(o12[0] * il, o12[1] * il); w.y = cvt_pk(o12[2] * il, o12[3] * il);
    *(uint2*)(yr + 32) = w;
    w.x = cvt_pk(o13[0] * il, o13[1] * il); w.y = cvt_pk(o13[2] * il, o13[3] * il);
    *(uint2*)(yr + 48) = w;
  }
  {
    const float il = 1.f / l2;
    const int q = 64 * s + 32 + l15;
    bf16_t* yr = Y + ((size_t)(b * T + q)) * 1024 + h * 64 + l4 * 4;
    uint2 w;
    w.x = cvt_pk(o20[0] * il, o20[1] * il); w.y = cvt_pk(o20[2] * il, o20[3] * il);
    *(uint2*)(yr + 0) = w;
    w.x = cvt_pk(o21[0] * il, o21[1] * il); w.y = cvt_pk(o21[2] * il, o21[3] * il);
    *(uint2*)(yr + 16) = w;
    w.x = cvt_pk(o22[0] * il, o22[1] * il); w.y = cvt_pk(o22[2] * il, o22[3] * il);
    *(uint2*)(yr + 32) = w;
    w.x = cvt_pk(o23[0] * il, o23[1] * il); w.y = cvt_pk(o23[2] * il, o23[3] * il);
    *(uint2*)(yr + 48) = w;
  }
  {
    const float il = 1.f / l3;
    const int q = 64 * s + 48 + l15;
    bf16_t* yr = Y + ((size_t)(b * T + q)) * 1024 + h * 64 + l4 * 4;
    uint2 w;
    w.x = cvt_pk(o30[0] * il, o30[1] * il); w.y = cvt_pk(o30[2] * il, o30[3] * il);
    *(uint2*)(yr + 0) = w;
    w.x = cvt_pk(o31[0] * il, o31[1] * il); w.y = cvt_pk(o31[2] * il, o31[3] * il);
    *(uint2*)(yr + 16) = w;
    w.x = cvt_pk(o32[0] * il, o32[1] * il); w.y = cvt_pk(o32[2] * il, o32[3] * il);
    *(uint2*)(yr + 32) = w;
    w.x = cvt_pk(o33[0] * il, o33[1] * il); w.y = cvt_pk(o33[2] * il, o33[3] * il);
    *(uint2*)(yr + 48) = w;
  }
}

// ---------------- launch ----------------
extern "C" void kernel_launch(void* const* d_in, const int* in_sizes, int n_in,
                              void* d_out, int out_size, void* d_ws, size_t ws_size,
                              hipStream_t stream) {
  const float* x      = (const float*)d_in[0];
  const float* w_attn = (const float*)d_in[1];
  const float* b_attn = (const float*)d_in[2];
  const float* w_proj = (const float*)d_in[3];
  const float* b_proj = (const float*)d_in[4];
  float* out = (float*)d_out;

  char* ws = (char*)d_ws;
  bf16_t* xb   = (bf16_t*)(ws);
  bf16_t* wab  = (bf16_t*)(ws + 16777216);
  bf16_t* wpb  = (bf16_t*)(ws + 23068672);
  bf16_t* qkvb = (bf16_t*)(ws + 25165824);   // q | k | vTiles (8M elems each)
  bf16_t* yb   = (bf16_t*)(ws + 75497472);

  cvt_f32_bf16<<<8192, 256, 0, stream>>>(x, xb, 2097152);
  cvt_f32_bf16<<<3072, 256, 0, stream>>>(w_attn, wab, 786432);
  cvt_f32_bf16<<<1024, 256, 0, stream>>>(w_proj, wpb, 262144);

  dim3 g1(24, 64);
  gemm_bt<0><<<g1, 256, 0, stream>>>(xb, wab, b_attn, (void*)qkvb, 8192, 3072, 1024);

  flash_attn<<<2048, 64, 0, stream>>>(qkvb, qkvb + 8388608, qkvb + 16777216, yb);

  dim3 g3(8, 64);
  gemm_bt<1><<<g3, 256, 0, stream>>>(yb, wpb, b_proj, (void*)out, 8192, 1024, 1024);
}

// Round 18
// 201.688 us; speedup vs baseline: 1.3358x; 1.1131x over previous
//
#include <hip/hip_runtime.h>
#include <hip/hip_bf16.h>
#include <stdint.h>

typedef __bf16 bf16_t;
typedef __bf16 bf16x8 __attribute__((ext_vector_type(8)));
typedef __bf16 bf16x4 __attribute__((ext_vector_type(4)));
typedef float f32x4 __attribute__((ext_vector_type(4)));

#define AS1 __attribute__((address_space(1)))
#define AS3 __attribute__((address_space(3)))

static __device__ __forceinline__ void gload_lds16(const void* g, void* l) {
  __builtin_amdgcn_global_load_lds((const AS1 void*)g, (AS3 void*)l, 16, 0, 0);
}

// v_cvt_pk_bf16_f32: dst.lo = bf16(lo), dst.hi = bf16(hi)
static __device__ __forceinline__ uint32_t cvt_pk(float lo, float hi) {
  uint32_t r;
  asm("v_cvt_pk_bf16_f32 %0, %1, %2" : "=v"(r) : "v"(lo), "v"(hi));
  return r;
}

// ---------------- fp32 -> bf16 convert (vectorized x4) ----------------
__global__ void cvt_f32_bf16(const float* __restrict__ in, bf16_t* __restrict__ out, int n4) {
  int i = blockIdx.x * blockDim.x + threadIdx.x;
  if (i >= n4) return;
  float4 v = ((const float4*)in)[i];
  bf16x4 o;
  o[0] = (bf16_t)v.x; o[1] = (bf16_t)v.y; o[2] = (bf16_t)v.z; o[3] = (bf16_t)v.w;
  *(bf16x4*)(out + (size_t)i * 4) = o;
}

// ---------------- GEMM C = A(MxK) * B(NxK)^T, bf16 in, fp32 acc ----------------
// BK=64 (halves barrier/drain count vs BK=32; 32 MFMA per K-step).
// LDS tiles are 128x64 bf16 (128B rows) -> chunk-XOR swizzle both sides
// (T2: store chunk c of row r at phys chunk c^(r&7); source pre-swizzled
// for global_load_lds; reads XOR the same way). XCD-aware block swizzle (T1).
// MODE 0: qkv epilogue. `which` is BLOCK-uniform (n0>>10): q scaled 0.125,
//   k row-major, v tile-blocked (bh, kt[32], d[64], ksigma[64]) with PACKED
//   8B stores (4 consecutive sigma positions per lane).
// MODE 1: proj epilogue (+bias, fp32 row-major out)
template<int MODE>
__global__ __launch_bounds__(256) void gemm_bt(
    const bf16_t* __restrict__ A, const bf16_t* __restrict__ Bw,
    const float* __restrict__ bias, void* __restrict__ Cout,
    int M, int N, int K)
{
  __shared__ bf16_t As[128 * 64];   // 16 KB, swizzled
  __shared__ bf16_t Bs[128 * 64];   // 16 KB, swizzled
  const int tid = threadIdx.x;
  const int wave = tid >> 6, lane = tid & 63;
  const int l15 = lane & 15, l4 = lane >> 4;
  const int nwgx = gridDim.x;
  const int fid = blockIdx.y * nwgx + blockIdx.x;
  const int qq = (nwgx * gridDim.y) >> 3;
  const int nid = (fid & 7) * qq + (fid >> 3);
  const int m0 = (nid / nwgx) * 128, n0 = (nid % nwgx) * 128;
  const int wm = (wave >> 1) * 64, wn = (wave & 1) * 64;
  f32x4 acc[4][4] = {};

  // staging: 4 gload_lds per matrix; instr j covers bytes j*4096 + tid*16
  // -> dest row = j*32 + (tid>>3), phys chunk = tid&7;
  // logical chunk = (tid&7) ^ (row&7), row&7 = (tid>>3)&7 (32 ≡ 0 mod 8)
  const int srow = tid >> 3;                                // 0..31
  const int schunk = ((tid & 7) ^ ((tid >> 3) & 7)) * 8;    // elem offset
  const bf16_t* gA = A + (size_t)(m0 + srow) * K + schunk;
  const bf16_t* gB = Bw + (size_t)(n0 + srow) * K + schunk;
  char* lA = (char*)As + tid * 16;
  char* lB = (char*)Bs + tid * 16;

  for (int k0 = 0; k0 < K; k0 += 64) {
    const bf16_t* ga = gA + k0;
    const bf16_t* gb = gB + k0;
    gload_lds16(ga,           lA);
    gload_lds16(ga + 32 * K,  lA + 4096);
    gload_lds16(ga + 64 * K,  lA + 8192);
    gload_lds16(ga + 96 * K,  lA + 12288);
    gload_lds16(gb,           lB);
    gload_lds16(gb + 32 * K,  lB + 4096);
    gload_lds16(gb + 64 * K,  lB + 8192);
    gload_lds16(gb + 96 * K,  lB + 12288);
    __syncthreads();
    bf16x8 af[4], bfr[4];
    // k-half 0 (logical chunks l4)
#pragma unroll
    for (int mt = 0; mt < 4; ++mt) {
      const int rr = wm + mt * 16 + l15;
      af[mt] = *(const bf16x8*)((const char*)As + rr * 128 + ((l4 ^ (rr & 7)) << 4));
    }
#pragma unroll
    for (int nt = 0; nt < 4; ++nt) {
      const int rr = wn + nt * 16 + l15;
      bfr[nt] = *(const bf16x8*)((const char*)Bs + rr * 128 + ((l4 ^ (rr & 7)) << 4));
    }
#pragma unroll
    for (int mt = 0; mt < 4; ++mt)
#pragma unroll
      for (int nt = 0; nt < 4; ++nt)
        acc[mt][nt] = __builtin_amdgcn_mfma_f32_16x16x32_bf16(af[mt], bfr[nt], acc[mt][nt], 0, 0, 0);
    // k-half 1 (logical chunks l4+4)
#pragma unroll
    for (int mt = 0; mt < 4; ++mt) {
      const int rr = wm + mt * 16 + l15;
      af[mt] = *(const bf16x8*)((const char*)As + rr * 128 + (((l4 + 4) ^ (rr & 7)) << 4));
    }
#pragma unroll
    for (int nt = 0; nt < 4; ++nt) {
      const int rr = wn + nt * 16 + l15;
      bfr[nt] = *(const bf16x8*)((const char*)Bs + rr * 128 + (((l4 + 4) ^ (rr & 7)) << 4));
    }
#pragma unroll
    for (int mt = 0; mt < 4; ++mt)
#pragma unroll
      for (int nt = 0; nt < 4; ++nt)
        acc[mt][nt] = __builtin_amdgcn_mfma_f32_16x16x32_bf16(af[mt], bfr[nt], acc[mt][nt], 0, 0, 0);
    __syncthreads();
  }

  if (MODE == 0) {
    bf16_t* qkv = (bf16_t*)Cout;
    const int which = n0 >> 10;   // block-uniform: 0=q 1=k 2=v
    if (which == 2) {
      // v: packed 8B stores -- 4 consecutive sigma positions per lane
#pragma unroll
      for (int mt = 0; mt < 4; ++mt) {
        const int rb = m0 + wm + mt * 16 + l4 * 4;   // row base (4-aligned)
        const int bb = rb >> 11, t = rb & 2047;
        const int ko = t & 63;                        // ko&3 == 0
        const int pos = (ko & 0x20) | ((ko & 0x0C) << 1) | ((ko & 0x10) >> 2);
        const size_t tilebase = 16777216 + ((size_t)(t >> 6) << 12) + pos;
#pragma unroll
        for (int nt = 0; nt < 4; ++nt) {
          const int col = n0 + wn + nt * 16 + l15;
          const float bv = bias[col];
          const int c = col & 1023;
          const int head = c >> 6, d = c & 63;
          const int bh2 = bb * 16 + head;
          const size_t idx = tilebase + (size_t)bh2 * 131072 + d * 64;
          uint2 w;
          w.x = cvt_pk(acc[mt][nt][0] + bv, acc[mt][nt][1] + bv);
          w.y = cvt_pk(acc[mt][nt][2] + bv, acc[mt][nt][3] + bv);
          *(uint2*)&qkv[idx] = w;
        }
      }
    } else {
      // q / k: scalar stores (d varies per lane -> 16-lane 32B runs)
#pragma unroll
      for (int mt = 0; mt < 4; ++mt) {
#pragma unroll
        for (int nt = 0; nt < 4; ++nt) {
          const int col = n0 + wn + nt * 16 + l15;
          const float bv = bias[col];
          const int c = col & 1023;
          const int head = c >> 6, d = c & 63;
#pragma unroll
          for (int i = 0; i < 4; ++i) {
            const int row = m0 + wm + mt * 16 + l4 * 4 + i;
            const int bb = row >> 11, t = row & 2047;
            const int bh2 = bb * 16 + head;
            float v = acc[mt][nt][i] + bv;
            size_t idx;
            if (which == 0) {
              v *= 0.125f;
              idx = ((size_t)(bh2 * 2048 + t) << 6) + d;
            } else {
              idx = 8388608 + ((size_t)(bh2 * 2048 + t) << 6) + d;
            }
            qkv[idx] = (bf16_t)v;
          }
        }
      }
    }
  } else {
    float* C = (float*)Cout;
#pragma unroll
    for (int mt = 0; mt < 4; ++mt) {
#pragma unroll
      for (int nt = 0; nt < 4; ++nt) {
        const int col = n0 + wn + nt * 16 + l15;
        const float bv = bias[col];
#pragma unroll
        for (int i = 0; i < 4; ++i) {
          const int row = m0 + wm + mt * 16 + l4 * 4 + i;
          C[(size_t)row * N + col] = acc[mt][nt][i] + bv;
        }
      }
    }
  }
}

// ---------------- one 16-q-row half-step (swapped-operand, in-lane SM) ----
static __device__ __forceinline__ void half_step(
    const bf16x8& kA0, const bf16x8& kB0, const bf16x8& kA1, const bf16x8& kB1,
    const bf16x8& kA2, const bf16x8& kB2, const bf16x8& kA3, const bf16x8& kB3,
    const bf16x8& vA0, const bf16x8& vB0, const bf16x8& vA1, const bf16x8& vB1,
    const bf16x8& vA2, const bf16x8& vB2, const bf16x8& vA3, const bf16x8& vB3,
    const bf16x8 aq0, const bf16x8 aq1,
    float& m_i, float& l_i,
    f32x4& o0, f32x4& o1, f32x4& o2, f32x4& o3,
    const bool diag, const int qb, const int kb)
{
  f32x4 s0 = {}, s1 = {}, s2 = {}, s3 = {};
  s0 = __builtin_amdgcn_mfma_f32_16x16x32_bf16(kA0, aq0, s0, 0, 0, 0);
  s0 = __builtin_amdgcn_mfma_f32_16x16x32_bf16(kB0, aq1, s0, 0, 0, 0);
  s1 = __builtin_amdgcn_mfma_f32_16x16x32_bf16(kA1, aq0, s1, 0, 0, 0);
  s1 = __builtin_amdgcn_mfma_f32_16x16x32_bf16(kB1, aq1, s1, 0, 0, 0);
  s2 = __builtin_amdgcn_mfma_f32_16x16x32_bf16(kA2, aq0, s2, 0, 0, 0);
  s2 = __builtin_amdgcn_mfma_f32_16x16x32_bf16(kB2, aq1, s2, 0, 0, 0);
  s3 = __builtin_amdgcn_mfma_f32_16x16x32_bf16(kA3, aq0, s3, 0, 0, 0);
  s3 = __builtin_amdgcn_mfma_f32_16x16x32_bf16(kB3, aq1, s3, 0, 0, 0);

  if (diag) {
#pragma unroll
    for (int i = 0; i < 4; ++i) {
      if (kb + i > qb)      s0[i] = -1e30f;
      if (16 + kb + i > qb) s1[i] = -1e30f;
      if (32 + kb + i > qb) s2[i] = -1e30f;
      if (48 + kb + i > qb) s3[i] = -1e30f;
    }
  }

  float pm = fmaxf(fmaxf(fmaxf(s0[0], s0[1]), fmaxf(s0[2], s0[3])),
                   fmaxf(fmaxf(s1[0], s1[1]), fmaxf(s1[2], s1[3])));
  pm = fmaxf(pm, fmaxf(fmaxf(fmaxf(s2[0], s2[1]), fmaxf(s2[2], s2[3])),
                       fmaxf(fmaxf(s3[0], s3[1]), fmaxf(s3[2], s3[3]))));
  pm = fmaxf(pm, __shfl_xor(pm, 16));
  pm = fmaxf(pm, __shfl_xor(pm, 32));

  // defer-max: skip rescale when the running max barely grows (P <= e^8)
  const bool keep = __all(pm - m_i <= 8.f);
  const float mn = keep ? m_i : fmaxf(m_i, pm);
  const float sc = keep ? 1.f : __expf(m_i - mn);
  m_i = mn;
#pragma unroll
  for (int i = 0; i < 4; ++i) {
    s0[i] = __expf(s0[i] - mn);
    s1[i] = __expf(s1[i] - mn);
    s2[i] = __expf(s2[i] - mn);
    s3[i] = __expf(s3[i] - mn);
  }
  float rs = ((s0[0] + s0[1]) + (s0[2] + s0[3])) + ((s1[0] + s1[1]) + (s1[2] + s1[3]))
           + ((s2[0] + s2[1]) + (s2[2] + s2[3])) + ((s3[0] + s3[1]) + (s3[2] + s3[3]));
  rs += __shfl_xor(rs, 16);
  rs += __shfl_xor(rs, 32);
  if (keep) {
    l_i = l_i + rs;
  } else {
    l_i = l_i * sc + rs;
    o0 *= sc; o1 *= sc; o2 *= sc; o3 *= sc;
  }

  union { uint32_t u[4]; bf16x8 v; } B0, B1;
  B0.u[0] = cvt_pk(s0[0], s0[1]); B0.u[1] = cvt_pk(s0[2], s0[3]);
  B0.u[2] = cvt_pk(s1[0], s1[1]); B0.u[3] = cvt_pk(s1[2], s1[3]);
  B1.u[0] = cvt_pk(s2[0], s2[1]); B1.u[1] = cvt_pk(s2[2], s2[3]);
  B1.u[2] = cvt_pk(s3[0], s3[1]); B1.u[3] = cvt_pk(s3[2], s3[3]);

  o0 = __builtin_amdgcn_mfma_f32_16x16x32_bf16(vA0, B0.v, o0, 0, 0, 0);
  o0 = __builtin_amdgcn_mfma_f32_16x16x32_bf16(vB0, B1.v, o0, 0, 0, 0);
  o1 = __builtin_amdgcn_mfma_f32_16x16x32_bf16(vA1, B0.v, o1, 0, 0, 0);
  o1 = __builtin_amdgcn_mfma_f32_16x16x32_bf16(vB1, B1.v, o1, 0, 0, 0);
  o2 = __builtin_amdgcn_mfma_f32_16x16x32_bf16(vA2, B0.v, o2, 0, 0, 0);
  o2 = __builtin_amdgcn_mfma_f32_16x16x32_bf16(vB2, B1.v, o2, 0, 0, 0);
  o3 = __builtin_amdgcn_mfma_f32_16x16x32_bf16(vA3, B0.v, o3, 0, 0, 0);
  o3 = __builtin_amdgcn_mfma_f32_16x16x32_bf16(vB3, B1.v, o3, 0, 0, 0);
}

// ---------------- causal flash attention: 64 q-rows / wave ---------------
// grid 2048 x 64 threads. Wave owns q-rows [64s, 64s+64) as FOUR 16-row
// halves sharing ONE K set + ONE V set per k-tile (halves the L2
// line-request count vs 32-row waves -- the confirmed R17 lever).
__global__ __launch_bounds__(64) void flash_attn(
    const bf16_t* __restrict__ Qg, const bf16_t* __restrict__ Kg,
    const bf16_t* __restrict__ VTg, bf16_t* __restrict__ Y)
{
  const int T = 2048, HS = 64;
  const int flat = blockIdx.x;         // 0..2047
  const int xcd = flat & 7;
  const int rest = flat >> 3;          // 0..255
  const int bh = xcd * 8 + (rest & 7); // 8 heads per XCD -> K/V L2-resident
  const int s = 31 - (rest >> 3);      // 64-row q-group, longest first
  const size_t baseQ = (size_t)bh * T * HS;   // Q,K: (bh, t, d)
  const size_t baseV = (size_t)bh * HS * T;   // V: (bh, kt, d, ksigma) tiles

  const int lane = threadIdx.x & 63;
  const int l15 = lane & 15, l4 = lane >> 4;

  const int bound = s;                 // last k-tile, same for all 4 halves
  const int kb = l4 * 4;
  const int qb0 = l15;
  const int qb1 = l15 + 16;
  const int qb2 = l15 + 32;
  const int qb3 = l15 + 48;

  const bf16_t* qr = Qg + baseQ + (size_t)(64 * s + l15) * HS;
  const bf16x8 aq00 = *(const bf16x8*)(qr + l4 * 8);
  const bf16x8 aq01 = *(const bf16x8*)(qr + 32 + l4 * 8);
  const bf16x8 aq10 = *(const bf16x8*)(qr + 16 * HS + l4 * 8);
  const bf16x8 aq11 = *(const bf16x8*)(qr + 16 * HS + 32 + l4 * 8);
  const bf16x8 aq20 = *(const bf16x8*)(qr + 32 * HS + l4 * 8);
  const bf16x8 aq21 = *(const bf16x8*)(qr + 32 * HS + 32 + l4 * 8);
  const bf16x8 aq30 = *(const bf16x8*)(qr + 48 * HS + l4 * 8);
  const bf16x8 aq31 = *(const bf16x8*)(qr + 48 * HS + 32 + l4 * 8);

  float m0 = -1e30f, l0 = 0.f, m1 = -1e30f, l1 = 0.f;
  float m2 = -1e30f, l2 = 0.f, m3 = -1e30f, l3 = 0.f;
  f32x4 o00 = {}, o01 = {}, o02 = {}, o03 = {};
  f32x4 o10 = {}, o11 = {}, o12 = {}, o13 = {};
  f32x4 o20 = {}, o21 = {}, o22 = {}, o23 = {};
  f32x4 o30 = {}, o31 = {}, o32 = {}, o33 = {};

  const bf16_t* kp = Kg + baseQ + (size_t)l15 * HS + l4 * 8;
  const bf16_t* vp = VTg + baseV + (size_t)l15 * 64 + l4 * 8;

  for (int kt = 0; kt <= bound; ++kt) {
    const bool dg = (kt == bound);
    const bf16x8 kA0 = *(const bf16x8*)(kp + 0);
    const bf16x8 kB0 = *(const bf16x8*)(kp + 32);
    const bf16x8 kA1 = *(const bf16x8*)(kp + 1024);
    const bf16x8 kB1 = *(const bf16x8*)(kp + 1024 + 32);
    const bf16x8 kA2 = *(const bf16x8*)(kp + 2048);
    const bf16x8 kB2 = *(const bf16x8*)(kp + 2048 + 32);
    const bf16x8 kA3 = *(const bf16x8*)(kp + 3072);
    const bf16x8 kB3 = *(const bf16x8*)(kp + 3072 + 32);
    const bf16x8 vA0 = *(const bf16x8*)(vp + 0);
    const bf16x8 vB0 = *(const bf16x8*)(vp + 32);
    const bf16x8 vA1 = *(const bf16x8*)(vp + 1024);
    const bf16x8 vB1 = *(const bf16x8*)(vp + 1024 + 32);
    const bf16x8 vA2 = *(const bf16x8*)(vp + 2048);
    const bf16x8 vB2 = *(const bf16x8*)(vp + 2048 + 32);
    const bf16x8 vA3 = *(const bf16x8*)(vp + 3072);
    const bf16x8 vB3 = *(const bf16x8*)(vp + 3072 + 32);

    half_step(kA0, kB0, kA1, kB1, kA2, kB2, kA3, kB3,
              vA0, vB0, vA1, vB1, vA2, vB2, vA3, vB3,
              aq00, aq01, m0, l0, o00, o01, o02, o03, dg, qb0, kb);
    half_step(kA0, kB0, kA1, kB1, kA2, kB2, kA3, kB3,
              vA0, vB0, vA1, vB1, vA2, vB2, vA3, vB3,
              aq10, aq11, m1, l1, o10, o11, o12, o13, dg, qb1, kb);
    half_step(kA0, kB0, kA1, kB1, kA2, kB2, kA3, kB3,
              vA0, vB0, vA1, vB1, vA2, vB2, vA3, vB3,
              aq20, aq21, m2, l2, o20, o21, o22, o23, dg, qb2, kb);
    half_step(kA0, kB0, kA1, kB1, kA2, kB2, kA3, kB3,
              vA0, vB0, vA1, vB1, vA2, vB2, vA3, vB3,
              aq30, aq31, m3, l3, o30, o31, o32, o33, dg, qb3, kb);

    kp += 4096;
    vp += 4096;
  }

  const int b = bh >> 4, h = bh & 15;
  {
    const float il = 1.f / l0;
    const int q = 64 * s + l15;
    bf16_t* yr = Y + ((size_t)(b * T + q)) * 1024 + h * 64 + l4 * 4;
    uint2 w;
    w.x = cvt_pk(o00[0] * il, o00[1] * il); w.y = cvt_pk(o00[2] * il, o00[3] * il);
    *(uint2*)(yr + 0) = w;
    w.x = cvt_pk(o01[0] * il, o01[1] * il); w.y = cvt_pk(o01[2] * il, o01[3] * il);
    *(uint2*)(yr + 16) = w;
    w.x = cvt_pk(o02[0] * il, o02[1] * il); w.y = cvt_pk(o02[2] * il, o02[3] * il);
    *(uint2*)(yr + 32) = w;
    w.x = cvt_pk(o03[0] * il, o03[1] * il); w.y = cvt_pk(o03[2] * il, o03[3] * il);
    *(uint2*)(yr + 48) = w;
  }
  {
    const float il = 1.f / l1;
    const int q = 64 * s + 16 + l15;
    bf16_t* yr = Y + ((size_t)(b * T + q)) * 1024 + h * 64 + l4 * 4;
    uint2 w;
    w.x = cvt_pk(o10[0] * il, o10[1] * il); w.y = cvt_pk(o10[2] * il, o10[3] * il);
    *(uint2*)(yr + 0) = w;
    w.x = cvt_pk(o11[0] * il, o11[1] * il); w.y = cvt_pk(o11[2] * il, o11[3] * il);
    *(uint2*)(yr + 16) = w;
    w.x = cvt_pk(o12[0] * il, o12[1] * il); w.y = cvt_pk(o12[2] * il, o12[3] * il);
    *(uint2*)(yr + 32) = w;
    w.x = cvt_pk(o13[0] * il, o13[1] * il); w.y = cvt_pk(o13[2] * il, o13[3] * il);
    *(uint2*)(yr + 48) = w;
  }
  {
    const float il = 1.f / l2;
    const int q = 64 * s + 32 + l15;
    bf16_t* yr = Y + ((size_t)(b * T + q)) * 1024 + h * 64 + l4 * 4;
    uint2 w;
    w.x = cvt_pk(o20[0] * il, o20[1] * il); w.y = cvt_pk(o20[2] * il, o20[3] * il);
    *(uint2*)(yr + 0) = w;
    w.x = cvt_pk(o21[0] * il, o21[1] * il); w.y = cvt_pk(o21[2] * il, o21[3] * il);
    *(uint2*)(yr + 16) = w;
    w.x = cvt_pk(o22[0] * il, o22[1] * il); w.y = cvt_pk(o22[2] * il, o22[3] * il);
    *(uint2*)(yr + 32) = w;
    w.x = cvt_pk(o23[0] * il, o23[1] * il); w.y = cvt_pk(o23[2] * il, o23[3] * il);
    *(uint2*)(yr + 48) = w;
  }
  {
    const float il = 1.f / l3;
    const int q = 64 * s + 48 + l15;
    bf16_t* yr = Y + ((size_t)(b * T + q)) * 1024 + h * 64 + l4 * 4;
    uint2 w;
    w.x = cvt_pk(o30[0] * il, o30[1] * il); w.y = cvt_pk(o30[2] * il, o30[3] * il);
    *(uint2*)(yr + 0) = w;
    w.x = cvt_pk(o31[0] * il, o31[1] * il); w.y = cvt_pk(o31[2] * il, o31[3] * il);
    *(uint2*)(yr + 16) = w;
    w.x = cvt_pk(o32[0] * il, o32[1] * il); w.y = cvt_pk(o32[2] * il, o32[3] * il);
    *(uint2*)(yr + 32) = w;
    w.x = cvt_pk(o33[0] * il, o33[1] * il); w.y = cvt_pk(o33[2] * il, o33[3] * il);
    *(uint2*)(yr + 48) = w;
  }
}

// ---------------- launch ----------------
extern "C" void kernel_launch(void* const* d_in, const int* in_sizes, int n_in,
                              void* d_out, int out_size, void* d_ws, size_t ws_size,
                              hipStream_t stream) {
  const float* x      = (const float*)d_in[0];
  const float* w_attn = (const float*)d_in[1];
  const float* b_attn = (const float*)d_in[2];
  const float* w_proj = (const float*)d_in[3];
  const float* b_proj = (const float*)d_in[4];
  float* out = (float*)d_out;

  char* ws = (char*)d_ws;
  bf16_t* xb   = (bf16_t*)(ws);
  bf16_t* wab  = (bf16_t*)(ws + 16777216);
  bf16_t* wpb  = (bf16_t*)(ws + 23068672);
  bf16_t* qkvb = (bf16_t*)(ws + 25165824);   // q | k | vTiles (8M elems each)
  bf16_t* yb   = (bf16_t*)(ws + 75497472);

  cvt_f32_bf16<<<8192, 256, 0, stream>>>(x, xb, 2097152);
  cvt_f32_bf16<<<3072, 256, 0, stream>>>(w_attn, wab, 786432);
  cvt_f32_bf16<<<1024, 256, 0, stream>>>(w_proj, wpb, 262144);

  dim3 g1(24, 64);
  gemm_bt<0><<<g1, 256, 0, stream>>>(xb, wab, b_attn, (void*)qkvb, 8192, 3072, 1024);

  flash_attn<<<2048, 64, 0, stream>>>(qkvb, qkvb + 8388608, qkvb + 16777216, yb);

  dim3 g3(8, 64);
  gemm_bt<1><<<g3, 256, 0, stream>>>(yb, wpb, b_proj, (void*)out, 8192, 1024, 1024);
}

// Round 21
// 197.863 us; speedup vs baseline: 1.3616x; 1.0193x over previous
//
#include <hip/hip_runtime.h>
#include <hip/hip_bf16.h>
#include <stdint.h>

typedef __bf16 bf16_t;
typedef __bf16 bf16x8 __attribute__((ext_vector_type(8)));
typedef __bf16 bf16x4 __attribute__((ext_vector_type(4)));
typedef float f32x4 __attribute__((ext_vector_type(4)));

#define AS1 __attribute__((address_space(1)))
#define AS3 __attribute__((address_space(3)))

static __device__ __forceinline__ void gload_lds16(const void* g, void* l) {
  __builtin_amdgcn_global_load_lds((const AS1 void*)g, (AS3 void*)l, 16, 0, 0);
}

// v_cvt_pk_bf16_f32: dst.lo = bf16(lo), dst.hi = bf16(hi)
static __device__ __forceinline__ uint32_t cvt_pk(float lo, float hi) {
  uint32_t r;
  asm("v_cvt_pk_bf16_f32 %0, %1, %2" : "=v"(r) : "v"(lo), "v"(hi));
  return r;
}

// ---------------- fused fp32 -> bf16 convert (x, w_attn, w_proj) ----------
// 3,145,728 float4-groups total = 6 per thread at 2048x256.
__global__ void cvt_fused(const float* __restrict__ x, const float* __restrict__ wa,
                          const float* __restrict__ wp, bf16_t* __restrict__ xb,
                          bf16_t* __restrict__ wab, bf16_t* __restrict__ wpb) {
  const int i = blockIdx.x * blockDim.x + threadIdx.x;   // 0..524287
#pragma unroll
  for (int k = 0; k < 6; ++k) {
    const int idx = i + k * 524288;
    const float4* src; bf16_t* dst; int off;
    if (idx < 2097152)      { src = (const float4*)x;  dst = xb;  off = idx; }
    else if (idx < 2883584) { src = (const float4*)wa; dst = wab; off = idx - 2097152; }
    else                    { src = (const float4*)wp; dst = wpb; off = idx - 2883584; }
    const float4 v = src[off];
    bf16x4 o;
    o[0] = (bf16_t)v.x; o[1] = (bf16_t)v.y; o[2] = (bf16_t)v.z; o[3] = (bf16_t)v.w;
    *(bf16x4*)(dst + (size_t)off * 4) = o;
  }
}

// ---------------- GEMM C = A(MxK) * B(NxK)^T, bf16 in, fp32 acc ----------------
// BK=64, chunk-XOR swizzled LDS (T2), XCD-aware block swizzle (T1).
// MODE 0: qkv epilogue (block-uniform `which`): q scaled 0.125 row-major,
//   k row-major, v tile-blocked (bh, kt[32], d[64], ksigma[64]) packed 8B.
// MODE 1: proj epilogue (+bias, fp32 row-major out)
template<int MODE>
__global__ __launch_bounds__(256) void gemm_bt(
    const bf16_t* __restrict__ A, const bf16_t* __restrict__ Bw,
    const float* __restrict__ bias, void* __restrict__ Cout,
    int M, int N, int K)
{
  __shared__ bf16_t As[128 * 64];
  __shared__ bf16_t Bs[128 * 64];
  const int tid = threadIdx.x;
  const int wave = tid >> 6, lane = tid & 63;
  const int l15 = lane & 15, l4 = lane >> 4;
  const int nwgx = gridDim.x;
  const int fid = blockIdx.y * nwgx + blockIdx.x;
  const int qq = (nwgx * gridDim.y) >> 3;
  const int nid = (fid & 7) * qq + (fid >> 3);
  const int m0 = (nid / nwgx) * 128, n0 = (nid % nwgx) * 128;
  const int wm = (wave >> 1) * 64, wn = (wave & 1) * 64;
  f32x4 acc[4][4] = {};

  const int srow = tid >> 3;
  const int schunk = ((tid & 7) ^ ((tid >> 3) & 7)) * 8;
  const bf16_t* gA = A + (size_t)(m0 + srow) * K + schunk;
  const bf16_t* gB = Bw + (size_t)(n0 + srow) * K + schunk;
  char* lA = (char*)As + tid * 16;
  char* lB = (char*)Bs + tid * 16;

  for (int k0 = 0; k0 < K; k0 += 64) {
    const bf16_t* ga = gA + k0;
    const bf16_t* gb = gB + k0;
    gload_lds16(ga,           lA);
    gload_lds16(ga + 32 * K,  lA + 4096);
    gload_lds16(ga + 64 * K,  lA + 8192);
    gload_lds16(ga + 96 * K,  lA + 12288);
    gload_lds16(gb,           lB);
    gload_lds16(gb + 32 * K,  lB + 4096);
    gload_lds16(gb + 64 * K,  lB + 8192);
    gload_lds16(gb + 96 * K,  lB + 12288);
    __syncthreads();
    bf16x8 af[4], bfr[4];
#pragma unroll
    for (int mt = 0; mt < 4; ++mt) {
      const int rr = wm + mt * 16 + l15;
      af[mt] = *(const bf16x8*)((const char*)As + rr * 128 + ((l4 ^ (rr & 7)) << 4));
    }
#pragma unroll
    for (int nt = 0; nt < 4; ++nt) {
      const int rr = wn + nt * 16 + l15;
      bfr[nt] = *(const bf16x8*)((const char*)Bs + rr * 128 + ((l4 ^ (rr & 7)) << 4));
    }
#pragma unroll
    for (int mt = 0; mt < 4; ++mt)
#pragma unroll
      for (int nt = 0; nt < 4; ++nt)
        acc[mt][nt] = __builtin_amdgcn_mfma_f32_16x16x32_bf16(af[mt], bfr[nt], acc[mt][nt], 0, 0, 0);
#pragma unroll
    for (int mt = 0; mt < 4; ++mt) {
      const int rr = wm + mt * 16 + l15;
      af[mt] = *(const bf16x8*)((const char*)As + rr * 128 + (((l4 + 4) ^ (rr & 7)) << 4));
    }
#pragma unroll
    for (int nt = 0; nt < 4; ++nt) {
      const int rr = wn + nt * 16 + l15;
      bfr[nt] = *(const bf16x8*)((const char*)Bs + rr * 128 + (((l4 + 4) ^ (rr & 7)) << 4));
    }
#pragma unroll
    for (int mt = 0; mt < 4; ++mt)
#pragma unroll
      for (int nt = 0; nt < 4; ++nt)
        acc[mt][nt] = __builtin_amdgcn_mfma_f32_16x16x32_bf16(af[mt], bfr[nt], acc[mt][nt], 0, 0, 0);
    __syncthreads();
  }

  if (MODE == 0) {
    bf16_t* qkv = (bf16_t*)Cout;
    const int which = n0 >> 10;
    if (which == 2) {
#pragma unroll
      for (int mt = 0; mt < 4; ++mt) {
        const int rb = m0 + wm + mt * 16 + l4 * 4;
        const int bb = rb >> 11, t = rb & 2047;
        const int ko = t & 63;
        const int pos = (ko & 0x20) | ((ko & 0x0C) << 1) | ((ko & 0x10) >> 2);
        const size_t tilebase = 16777216 + ((size_t)(t >> 6) << 12) + pos;
#pragma unroll
        for (int nt = 0; nt < 4; ++nt) {
          const int col = n0 + wn + nt * 16 + l15;
          const float bv = bias[col];
          const int c = col & 1023;
          const int head = c >> 6, d = c & 63;
          const int bh2 = bb * 16 + head;
          const size_t idx = tilebase + (size_t)bh2 * 131072 + d * 64;
          uint2 w;
          w.x = cvt_pk(acc[mt][nt][0] + bv, acc[mt][nt][1] + bv);
          w.y = cvt_pk(acc[mt][nt][2] + bv, acc[mt][nt][3] + bv);
          *(uint2*)&qkv[idx] = w;
        }
      }
    } else {
#pragma unroll
      for (int mt = 0; mt < 4; ++mt) {
#pragma unroll
        for (int nt = 0; nt < 4; ++nt) {
          const int col = n0 + wn + nt * 16 + l15;
          const float bv = bias[col];
          const int c = col & 1023;
          const int head = c >> 6, d = c & 63;
#pragma unroll
          for (int i = 0; i < 4; ++i) {
            const int row = m0 + wm + mt * 16 + l4 * 4 + i;
            const int bb = row >> 11, t = row & 2047;
            const int bh2 = bb * 16 + head;
            float v = acc[mt][nt][i] + bv;
            size_t idx;
            if (which == 0) {
              v *= 0.125f;
              idx = ((size_t)(bh2 * 2048 + t) << 6) + d;
            } else {
              idx = 8388608 + ((size_t)(bh2 * 2048 + t) << 6) + d;
            }
            qkv[idx] = (bf16_t)v;
          }
        }
      }
    }
  } else {
    float* C = (float*)Cout;
#pragma unroll
    for (int mt = 0; mt < 4; ++mt) {
#pragma unroll
      for (int nt = 0; nt < 4; ++nt) {
        const int col = n0 + wn + nt * 16 + l15;
        const float bv = bias[col];
#pragma unroll
        for (int i = 0; i < 4; ++i) {
          const int row = m0 + wm + mt * 16 + l4 * 4 + i;
          C[(size_t)row * N + col] = acc[mt][nt][i] + bv;
        }
      }
    }
  }
}

// ---------------- one 16-q-row half-step (swapped-operand, in-lane SM) ----
static __device__ __forceinline__ void half_step(
    const bf16x8& kA0, const bf16x8& kB0, const bf16x8& kA1, const bf16x8& kB1,
    const bf16x8& kA2, const bf16x8& kB2, const bf16x8& kA3, const bf16x8& kB3,
    const bf16x8& vA0, const bf16x8& vB0, const bf16x8& vA1, const bf16x8& vB1,
    const bf16x8& vA2, const bf16x8& vB2, const bf16x8& vA3, const bf16x8& vB3,
    const bf16x8 aq0, const bf16x8 aq1,
    float& m_i, float& l_i,
    f32x4& o0, f32x4& o1, f32x4& o2, f32x4& o3,
    const bool diag, const int qb, const int kb)
{
  f32x4 s0 = {}, s1 = {}, s2 = {}, s3 = {};
  s0 = __builtin_amdgcn_mfma_f32_16x16x32_bf16(kA0, aq0, s0, 0, 0, 0);
  s0 = __builtin_amdgcn_mfma_f32_16x16x32_bf16(kB0, aq1, s0, 0, 0, 0);
  s1 = __builtin_amdgcn_mfma_f32_16x16x32_bf16(kA1, aq0, s1, 0, 0, 0);
  s1 = __builtin_amdgcn_mfma_f32_16x16x32_bf16(kB1, aq1, s1, 0, 0, 0);
  s2 = __builtin_amdgcn_mfma_f32_16x16x32_bf16(kA2, aq0, s2, 0, 0, 0);
  s2 = __builtin_amdgcn_mfma_f32_16x16x32_bf16(kB2, aq1, s2, 0, 0, 0);
  s3 = __builtin_amdgcn_mfma_f32_16x16x32_bf16(kA3, aq0, s3, 0, 0, 0);
  s3 = __builtin_amdgcn_mfma_f32_16x16x32_bf16(kB3, aq1, s3, 0, 0, 0);

  if (diag) {
#pragma unroll
    for (int i = 0; i < 4; ++i) {
      if (kb + i > qb)      s0[i] = -1e30f;
      if (16 + kb + i > qb) s1[i] = -1e30f;
      if (32 + kb + i > qb) s2[i] = -1e30f;
      if (48 + kb + i > qb) s3[i] = -1e30f;
    }
  }

  float pm = fmaxf(fmaxf(fmaxf(s0[0], s0[1]), fmaxf(s0[2], s0[3])),
                   fmaxf(fmaxf(s1[0], s1[1]), fmaxf(s1[2], s1[3])));
  pm = fmaxf(pm, fmaxf(fmaxf(fmaxf(s2[0], s2[1]), fmaxf(s2[2], s2[3])),
                       fmaxf(fmaxf(s3[0], s3[1]), fmaxf(s3[2], s3[3]))));
  pm = fmaxf(pm, __shfl_xor(pm, 16));
  pm = fmaxf(pm, __shfl_xor(pm, 32));

  const bool keep = __all(pm - m_i <= 8.f);
  const float mn = keep ? m_i : fmaxf(m_i, pm);
  const float sc = keep ? 1.f : __expf(m_i - mn);
  m_i = mn;
#pragma unroll
  for (int i = 0; i < 4; ++i) {
    s0[i] = __expf(s0[i] - mn);
    s1[i] = __expf(s1[i] - mn);
    s2[i] = __expf(s2[i] - mn);
    s3[i] = __expf(s3[i] - mn);
  }
  float rs = ((s0[0] + s0[1]) + (s0[2] + s0[3])) + ((s1[0] + s1[1]) + (s1[2] + s1[3]))
           + ((s2[0] + s2[1]) + (s2[2] + s2[3])) + ((s3[0] + s3[1]) + (s3[2] + s3[3]));
  rs += __shfl_xor(rs, 16);
  rs += __shfl_xor(rs, 32);
  if (keep) {
    l_i = l_i + rs;
  } else {
    l_i = l_i * sc + rs;
    o0 *= sc; o1 *= sc; o2 *= sc; o3 *= sc;
  }

  union { uint32_t u[4]; bf16x8 v; } B0, B1;
  B0.u[0] = cvt_pk(s0[0], s0[1]); B0.u[1] = cvt_pk(s0[2], s0[3]);
  B0.u[2] = cvt_pk(s1[0], s1[1]); B0.u[3] = cvt_pk(s1[2], s1[3]);
  B1.u[0] = cvt_pk(s2[0], s2[1]); B1.u[1] = cvt_pk(s2[2], s2[3]);
  B1.u[2] = cvt_pk(s3[0], s3[1]); B1.u[3] = cvt_pk(s3[2], s3[3]);

  o0 = __builtin_amdgcn_mfma_f32_16x16x32_bf16(vA0, B0.v, o0, 0, 0, 0);
  o0 = __builtin_amdgcn_mfma_f32_16x16x32_bf16(vB0, B1.v, o0, 0, 0, 0);
  o1 = __builtin_amdgcn_mfma_f32_16x16x32_bf16(vA1, B0.v, o1, 0, 0, 0);
  o1 = __builtin_amdgcn_mfma_f32_16x16x32_bf16(vB1, B1.v, o1, 0, 0, 0);
  o2 = __builtin_amdgcn_mfma_f32_16x16x32_bf16(vA2, B0.v, o2, 0, 0, 0);
  o2 = __builtin_amdgcn_mfma_f32_16x16x32_bf16(vB2, B1.v, o2, 0, 0, 0);
  o3 = __builtin_amdgcn_mfma_f32_16x16x32_bf16(vA3, B0.v, o3, 0, 0, 0);
  o3 = __builtin_amdgcn_mfma_f32_16x16x32_bf16(vB3, B1.v, o3, 0, 0, 0);
}

// ---------------- causal flash attention: 64 q-rows / wave ---------------
// grid 2048 x 64 threads. Wave owns q-rows [64s, 64s+64) as FOUR 16-row
// halves sharing ONE K set + ONE V set per k-tile (halves the L2
// line-request count vs 32-row waves -- the confirmed R17 lever).
// NOTE: any added structure on this kernel (register-rotated prefetch,
// split-K LDS merge) produced NaN 3x at ~200+ VGPR despite clean
// semantics -- do not extend; this is the validated plateau.
__global__ __launch_bounds__(64) void flash_attn(
    const bf16_t* __restrict__ Qg, const bf16_t* __restrict__ Kg,
    const bf16_t* __restrict__ VTg, bf16_t* __restrict__ Y)
{
  const int T = 2048, HS = 64;
  const int flat = blockIdx.x;         // 0..2047
  const int xcd = flat & 7;
  const int rest = flat >> 3;          // 0..255
  const int bh = xcd * 8 + (rest & 7); // 8 heads per XCD -> K/V L2-resident
  const int s = 31 - (rest >> 3);      // 64-row q-group, longest first
  const size_t baseQ = (size_t)bh * T * HS;   // Q,K: (bh, t, d)
  const size_t baseV = (size_t)bh * HS * T;   // V: (bh, kt, d, ksigma) tiles

  const int lane = threadIdx.x & 63;
  const int l15 = lane & 15, l4 = lane >> 4;

  const int bound = s;                 // last k-tile, same for all 4 halves
  const int kb = l4 * 4;
  const int qb0 = l15;
  const int qb1 = l15 + 16;
  const int qb2 = l15 + 32;
  const int qb3 = l15 + 48;

  const bf16_t* qr = Qg + baseQ + (size_t)(64 * s + l15) * HS;
  const bf16x8 aq00 = *(const bf16x8*)(qr + l4 * 8);
  const bf16x8 aq01 = *(const bf16x8*)(qr + 32 + l4 * 8);
  const bf16x8 aq10 = *(const bf16x8*)(qr + 16 * HS + l4 * 8);
  const bf16x8 aq11 = *(const bf16x8*)(qr + 16 * HS + 32 + l4 * 8);
  const bf16x8 aq20 = *(const bf16x8*)(qr + 32 * HS + l4 * 8);
  const bf16x8 aq21 = *(const bf16x8*)(qr + 32 * HS + 32 + l4 * 8);
  const bf16x8 aq30 = *(const bf16x8*)(qr + 48 * HS + l4 * 8);
  const bf16x8 aq31 = *(const bf16x8*)(qr + 48 * HS + 32 + l4 * 8);

  float m0 = -1e30f, l0 = 0.f, m1 = -1e30f, l1 = 0.f;
  float m2 = -1e30f, l2 = 0.f, m3 = -1e30f, l3 = 0.f;
  f32x4 o00 = {}, o01 = {}, o02 = {}, o03 = {};
  f32x4 o10 = {}, o11 = {}, o12 = {}, o13 = {};
  f32x4 o20 = {}, o21 = {}, o22 = {}, o23 = {};
  f32x4 o30 = {}, o31 = {}, o32 = {}, o33 = {};

  const bf16_t* kp = Kg + baseQ + (size_t)l15 * HS + l4 * 8;
  const bf16_t* vp = VTg + baseV + (size_t)l15 * 64 + l4 * 8;

  for (int kt = 0; kt <= bound; ++kt) {
    const bool dg = (kt == bound);
    const bf16x8 kA0 = *(const bf16x8*)(kp + 0);
    const bf16x8 kB0 = *(const bf16x8*)(kp + 32);
    const bf16x8 kA1 = *(const bf16x8*)(kp + 1024);
    const bf16x8 kB1 = *(const bf16x8*)(kp + 1024 + 32);
    const bf16x8 kA2 = *(const bf16x8*)(kp + 2048);
    const bf16x8 kB2 = *(const bf16x8*)(kp + 2048 + 32);
    const bf16x8 kA3 = *(const bf16x8*)(kp + 3072);
    const bf16x8 kB3 = *(const bf16x8*)(kp + 3072 + 32);
    const bf16x8 vA0 = *(const bf16x8*)(vp + 0);
    const bf16x8 vB0 = *(const bf16x8*)(vp + 32);
    const bf16x8 vA1 = *(const bf16x8*)(vp + 1024);
    const bf16x8 vB1 = *(const bf16x8*)(vp + 1024 + 32);
    const bf16x8 vA2 = *(const bf16x8*)(vp + 2048);
    const bf16x8 vB2 = *(const bf16x8*)(vp + 2048 + 32);
    const bf16x8 vA3 = *(const bf16x8*)(vp + 3072);
    const bf16x8 vB3 = *(const bf16x8*)(vp + 3072 + 32);

    half_step(kA0, kB0, kA1, kB1, kA2, kB2, kA3, kB3,
              vA0, vB0, vA1, vB1, vA2, vB2, vA3, vB3,
              aq00, aq01, m0, l0, o00, o01, o02, o03, dg, qb0, kb);
    half_step(kA0, kB0, kA1, kB1, kA2, kB2, kA3, kB3,
              vA0, vB0, vA1, vB1, vA2, vB2, vA3, vB3,
              aq10, aq11, m1, l1, o10, o11, o12, o13, dg, qb1, kb);
    half_step(kA0, kB0, kA1, kB1, kA2, kB2, kA3, kB3,
              vA0, vB0, vA1, vB1, vA2, vB2, vA3, vB3,
              aq20, aq21, m2, l2, o20, o21, o22, o23, dg, qb2, kb);
    half_step(kA0, kB0, kA1, kB1, kA2, kB2, kA3, kB3,
              vA0, vB0, vA1, vB1, vA2, vB2, vA3, vB3,
              aq30, aq31, m3, l3, o30, o31, o32, o33, dg, qb3, kb);

    kp += 4096;
    vp += 4096;
  }

  const int b = bh >> 4, h = bh & 15;
  {
    const float il = 1.f / l0;
    const int q = 64 * s + l15;
    bf16_t* yr = Y + ((size_t)(b * T + q)) * 1024 + h * 64 + l4 * 4;
    uint2 w;
    w.x = cvt_pk(o00[0] * il, o00[1] * il); w.y = cvt_pk(o00[2] * il, o00[3] * il);
    *(uint2*)(yr + 0) = w;
    w.x = cvt_pk(o01[0] * il, o01[1] * il); w.y = cvt_pk(o01[2] * il, o01[3] * il);
    *(uint2*)(yr + 16) = w;
    w.x = cvt_pk(o02[0] * il, o02[1] * il); w.y = cvt_pk(o02[2] * il, o02[3] * il);
    *(uint2*)(yr + 32) = w;
    w.x = cvt_pk(o03[0] * il, o03[1] * il); w.y = cvt_pk(o03[2] * il, o03[3] * il);
    *(uint2*)(yr + 48) = w;
  }
  {
    const float il = 1.f / l1;
    const int q = 64 * s + 16 + l15;
    bf16_t* yr = Y + ((size_t)(b * T + q)) * 1024 + h * 64 + l4 * 4;
    uint2 w;
    w.x = cvt_pk(o10[0] * il, o10[1] * il); w.y = cvt_pk(o10[2] * il, o10[3] * il);
    *(uint2*)(yr + 0) = w;
    w.x = cvt_pk(o11[0] * il, o11[1] * il); w.y = cvt_pk(o11[2] * il, o11[3] * il);
    *(uint2*)(yr + 16) = w;
    w.x = cvt_pk(o12[0] * il, o12[1] * il); w.y = cvt_pk(o12[2] * il, o12[3] * il);
    *(uint2*)(yr + 32) = w;
    w.x = cvt_pk(o13[0] * il, o13[1] * il); w.y = cvt_pk(o13[2] * il, o13[3] * il);
    *(uint2*)(yr + 48) = w;
  }
  {
    const float il = 1.f / l2;
    const int q = 64 * s + 32 + l15;
    bf16_t* yr = Y + ((size_t)(b * T + q)) * 1024 + h * 64 + l4 * 4;
    uint2 w;
    w.x = cvt_pk(o20[0] * il, o20[1] * il); w.y = cvt_pk(o20[2] * il, o20[3] * il);
    *(uint2*)(yr + 0) = w;
    w.x = cvt_pk(o21[0] * il, o21[1] * il); w.y = cvt_pk(o21[2] * il, o21[3] * il);
    *(uint2*)(yr + 16) = w;
    w.x = cvt_pk(o22[0] * il, o22[1] * il); w.y = cvt_pk(o22[2] * il, o22[3] * il);
    *(uint2*)(yr + 32) = w;
    w.x = cvt_pk(o23[0] * il, o23[1] * il); w.y = cvt_pk(o23[2] * il, o23[3] * il);
    *(uint2*)(yr + 48) = w;
  }
  {
    const float il = 1.f / l3;
    const int q = 64 * s + 48 + l15;
    bf16_t* yr = Y + ((size_t)(b * T + q)) * 1024 + h * 64 + l4 * 4;
    uint2 w;
    w.x = cvt_pk(o30[0] * il, o30[1] * il); w.y = cvt_pk(o30[2] * il, o30[3] * il);
    *(uint2*)(yr + 0) = w;
    w.x = cvt_pk(o31[0] * il, o31[1] * il); w.y = cvt_pk(o31[2] * il, o31[3] * il);
    *(uint2*)(yr + 16) = w;
    w.x = cvt_pk(o32[0] * il, o32[1] * il); w.y = cvt_pk(o32[2] * il, o32[3] * il);
    *(uint2*)(yr + 32) = w;
    w.x = cvt_pk(o33[0] * il, o33[1] * il); w.y = cvt_pk(o33[2] * il, o33[3] * il);
    *(uint2*)(yr + 48) = w;
  }
}

// ---------------- launch ----------------
extern "C" void kernel_launch(void* const* d_in, const int* in_sizes, int n_in,
                              void* d_out, int out_size, void* d_ws, size_t ws_size,
                              hipStream_t stream) {
  const float* x      = (const float*)d_in[0];
  const float* w_attn = (const float*)d_in[1];
  const float* b_attn = (const float*)d_in[2];
  const float* w_proj = (const float*)d_in[3];
  const float* b_proj = (const float*)d_in[4];
  float* out = (float*)d_out;

  char* ws = (char*)d_ws;
  bf16_t* xb   = (bf16_t*)(ws);
  bf16_t* wab  = (bf16_t*)(ws + 16777216);
  bf16_t* wpb  = (bf16_t*)(ws + 23068672);
  bf16_t* qkvb = (bf16_t*)(ws + 25165824);   // q | k | vTiles (8M elems each)
  bf16_t* yb   = (bf16_t*)(ws + 75497472);

  cvt_fused<<<2048, 256, 0, stream>>>(x, w_attn, w_proj, xb, wab, wpb);

  dim3 g1(24, 64);
  gemm_bt<0><<<g1, 256, 0, stream>>>(xb, wab, b_attn, (void*)qkvb, 8192, 3072, 1024);

  flash_attn<<<2048, 64, 0, stream>>>(qkvb, qkvb + 8388608, qkvb + 16777216, yb);

  dim3 g3(8, 64);
  gemm_bt<1><<<g3, 256, 0, stream>>>(yb, wpb, b_proj, (void*)out, 8192, 1024, 1024);
}

// Round 22
// 197.233 us; speedup vs baseline: 1.3660x; 1.0032x over previous
//
#include <hip/hip_runtime.h>
#include <hip/hip_bf16.h>
#include <stdint.h>

typedef __bf16 bf16_t;
typedef __bf16 bf16x8 __attribute__((ext_vector_type(8)));
typedef __bf16 bf16x4 __attribute__((ext_vector_type(4)));
typedef float f32x4 __attribute__((ext_vector_type(4)));

#define AS1 __attribute__((address_space(1)))
#define AS3 __attribute__((address_space(3)))

static __device__ __forceinline__ void gload_lds16(const void* g, void* l) {
  __builtin_amdgcn_global_load_lds((const AS1 void*)g, (AS3 void*)l, 16, 0, 0);
}

// v_cvt_pk_bf16_f32: dst.lo = bf16(lo), dst.hi = bf16(hi)
static __device__ __forceinline__ uint32_t cvt_pk(float lo, float hi) {
  uint32_t r;
  asm("v_cvt_pk_bf16_f32 %0, %1, %2" : "=v"(r) : "v"(lo), "v"(hi));
  return r;
}

// ---------------- fused fp32 -> bf16 convert (x, w_attn, w_proj) ----------
// 3,145,728 float4-groups total = 6 per thread at 2048x256.
__global__ void cvt_fused(const float* __restrict__ x, const float* __restrict__ wa,
                          const float* __restrict__ wp, bf16_t* __restrict__ xb,
                          bf16_t* __restrict__ wab, bf16_t* __restrict__ wpb) {
  const int i = blockIdx.x * blockDim.x + threadIdx.x;   // 0..524287
#pragma unroll
  for (int k = 0; k < 6; ++k) {
    const int idx = i + k * 524288;
    const float4* src; bf16_t* dst; int off;
    if (idx < 2097152)      { src = (const float4*)x;  dst = xb;  off = idx; }
    else if (idx < 2883584) { src = (const float4*)wa; dst = wab; off = idx - 2097152; }
    else                    { src = (const float4*)wp; dst = wpb; off = idx - 2883584; }
    const float4 v = src[off];
    bf16x4 o;
    o[0] = (bf16_t)v.x; o[1] = (bf16_t)v.y; o[2] = (bf16_t)v.z; o[3] = (bf16_t)v.w;
    *(bf16x4*)(dst + (size_t)off * 4) = o;
  }
}

// ---------------- GEMM C = A(MxK) * B(NxK)^T, bf16 in, fp32 acc ----------------
// BK=64, chunk-XOR swizzled LDS (T2), XCD-aware block swizzle (T1).
// MODE 0: qkv epilogue (block-uniform `which`): q scaled 0.125 row-major,
//   k row-major, v tile-blocked (bh, kt[32], d[64], ksigma[64]) packed 8B.
// MODE 1: proj epilogue (+bias, fp32 row-major out)
template<int MODE>
__global__ __launch_bounds__(256) void gemm_bt(
    const bf16_t* __restrict__ A, const bf16_t* __restrict__ Bw,
    const float* __restrict__ bias, void* __restrict__ Cout,
    int M, int N, int K)
{
  __shared__ bf16_t As[128 * 64];
  __shared__ bf16_t Bs[128 * 64];
  const int tid = threadIdx.x;
  const int wave = tid >> 6, lane = tid & 63;
  const int l15 = lane & 15, l4 = lane >> 4;
  const int nwgx = gridDim.x;
  const int fid = blockIdx.y * nwgx + blockIdx.x;
  const int qq = (nwgx * gridDim.y) >> 3;
  const int nid = (fid & 7) * qq + (fid >> 3);
  const int m0 = (nid / nwgx) * 128, n0 = (nid % nwgx) * 128;
  const int wm = (wave >> 1) * 64, wn = (wave & 1) * 64;
  f32x4 acc[4][4] = {};

  const int srow = tid >> 3;
  const int schunk = ((tid & 7) ^ ((tid >> 3) & 7)) * 8;
  const bf16_t* gA = A + (size_t)(m0 + srow) * K + schunk;
  const bf16_t* gB = Bw + (size_t)(n0 + srow) * K + schunk;
  char* lA = (char*)As + tid * 16;
  char* lB = (char*)Bs + tid * 16;

  for (int k0 = 0; k0 < K; k0 += 64) {
    const bf16_t* ga = gA + k0;
    const bf16_t* gb = gB + k0;
    gload_lds16(ga,           lA);
    gload_lds16(ga + 32 * K,  lA + 4096);
    gload_lds16(ga + 64 * K,  lA + 8192);
    gload_lds16(ga + 96 * K,  lA + 12288);
    gload_lds16(gb,           lB);
    gload_lds16(gb + 32 * K,  lB + 4096);
    gload_lds16(gb + 64 * K,  lB + 8192);
    gload_lds16(gb + 96 * K,  lB + 12288);
    __syncthreads();
    bf16x8 af[4], bfr[4];
#pragma unroll
    for (int mt = 0; mt < 4; ++mt) {
      const int rr = wm + mt * 16 + l15;
      af[mt] = *(const bf16x8*)((const char*)As + rr * 128 + ((l4 ^ (rr & 7)) << 4));
    }
#pragma unroll
    for (int nt = 0; nt < 4; ++nt) {
      const int rr = wn + nt * 16 + l15;
      bfr[nt] = *(const bf16x8*)((const char*)Bs + rr * 128 + ((l4 ^ (rr & 7)) << 4));
    }
#pragma unroll
    for (int mt = 0; mt < 4; ++mt)
#pragma unroll
      for (int nt = 0; nt < 4; ++nt)
        acc[mt][nt] = __builtin_amdgcn_mfma_f32_16x16x32_bf16(af[mt], bfr[nt], acc[mt][nt], 0, 0, 0);
#pragma unroll
    for (int mt = 0; mt < 4; ++mt) {
      const int rr = wm + mt * 16 + l15;
      af[mt] = *(const bf16x8*)((const char*)As + rr * 128 + (((l4 + 4) ^ (rr & 7)) << 4));
    }
#pragma unroll
    for (int nt = 0; nt < 4; ++nt) {
      const int rr = wn + nt * 16 + l15;
      bfr[nt] = *(const bf16x8*)((const char*)Bs + rr * 128 + (((l4 + 4) ^ (rr & 7)) << 4));
    }
#pragma unroll
    for (int mt = 0; mt < 4; ++mt)
#pragma unroll
      for (int nt = 0; nt < 4; ++nt)
        acc[mt][nt] = __builtin_amdgcn_mfma_f32_16x16x32_bf16(af[mt], bfr[nt], acc[mt][nt], 0, 0, 0);
    __syncthreads();
  }

  if (MODE == 0) {
    bf16_t* qkv = (bf16_t*)Cout;
    const int which = n0 >> 10;
    if (which == 2) {
#pragma unroll
      for (int mt = 0; mt < 4; ++mt) {
        const int rb = m0 + wm + mt * 16 + l4 * 4;
        const int bb = rb >> 11, t = rb & 2047;
        const int ko = t & 63;
        const int pos = (ko & 0x20) | ((ko & 0x0C) << 1) | ((ko & 0x10) >> 2);
        const size_t tilebase = 16777216 + ((size_t)(t >> 6) << 12) + pos;
#pragma unroll
        for (int nt = 0; nt < 4; ++nt) {
          const int col = n0 + wn + nt * 16 + l15;
          const float bv = bias[col];
          const int c = col & 1023;
          const int head = c >> 6, d = c & 63;
          const int bh2 = bb * 16 + head;
          const size_t idx = tilebase + (size_t)bh2 * 131072 + d * 64;
          uint2 w;
          w.x = cvt_pk(acc[mt][nt][0] + bv, acc[mt][nt][1] + bv);
          w.y = cvt_pk(acc[mt][nt][2] + bv, acc[mt][nt][3] + bv);
          *(uint2*)&qkv[idx] = w;
        }
      }
    } else {
#pragma unroll
      for (int mt = 0; mt < 4; ++mt) {
#pragma unroll
        for (int nt = 0; nt < 4; ++nt) {
          const int col = n0 + wn + nt * 16 + l15;
          const float bv = bias[col];
          const int c = col & 1023;
          const int head = c >> 6, d = c & 63;
#pragma unroll
          for (int i = 0; i < 4; ++i) {
            const int row = m0 + wm + mt * 16 + l4 * 4 + i;
            const int bb = row >> 11, t = row & 2047;
            const int bh2 = bb * 16 + head;
            float v = acc[mt][nt][i] + bv;
            size_t idx;
            if (which == 0) {
              v *= 0.125f;
              idx = ((size_t)(bh2 * 2048 + t) << 6) + d;
            } else {
              idx = 8388608 + ((size_t)(bh2 * 2048 + t) << 6) + d;
            }
            qkv[idx] = (bf16_t)v;
          }
        }
      }
    }
  } else {
    float* C = (float*)Cout;
#pragma unroll
    for (int mt = 0; mt < 4; ++mt) {
#pragma unroll
      for (int nt = 0; nt < 4; ++nt) {
        const int col = n0 + wn + nt * 16 + l15;
        const float bv = bias[col];
#pragma unroll
        for (int i = 0; i < 4; ++i) {
          const int row = m0 + wm + mt * 16 + l4 * 4 + i;
          C[(size_t)row * N + col] = acc[mt][nt][i] + bv;
        }
      }
    }
  }
}

// ---------------- one 16-q-row half-step (swapped-operand, in-lane SM) ----
static __device__ __forceinline__ void half_step(
    const bf16x8& kA0, const bf16x8& kB0, const bf16x8& kA1, const bf16x8& kB1,
    const bf16x8& kA2, const bf16x8& kB2, const bf16x8& kA3, const bf16x8& kB3,
    const bf16x8& vA0, const bf16x8& vB0, const bf16x8& vA1, const bf16x8& vB1,
    const bf16x8& vA2, const bf16x8& vB2, const bf16x8& vA3, const bf16x8& vB3,
    const bf16x8 aq0, const bf16x8 aq1,
    float& m_i, float& l_i,
    f32x4& o0, f32x4& o1, f32x4& o2, f32x4& o3,
    const bool diag, const int qb, const int kb)
{
  f32x4 s0 = {}, s1 = {}, s2 = {}, s3 = {};
  s0 = __builtin_amdgcn_mfma_f32_16x16x32_bf16(kA0, aq0, s0, 0, 0, 0);
  s0 = __builtin_amdgcn_mfma_f32_16x16x32_bf16(kB0, aq1, s0, 0, 0, 0);
  s1 = __builtin_amdgcn_mfma_f32_16x16x32_bf16(kA1, aq0, s1, 0, 0, 0);
  s1 = __builtin_amdgcn_mfma_f32_16x16x32_bf16(kB1, aq1, s1, 0, 0, 0);
  s2 = __builtin_amdgcn_mfma_f32_16x16x32_bf16(kA2, aq0, s2, 0, 0, 0);
  s2 = __builtin_amdgcn_mfma_f32_16x16x32_bf16(kB2, aq1, s2, 0, 0, 0);
  s3 = __builtin_amdgcn_mfma_f32_16x16x32_bf16(kA3, aq0, s3, 0, 0, 0);
  s3 = __builtin_amdgcn_mfma_f32_16x16x32_bf16(kB3, aq1, s3, 0, 0, 0);

  if (diag) {
#pragma unroll
    for (int i = 0; i < 4; ++i) {
      if (kb + i > qb)      s0[i] = -1e30f;
      if (16 + kb + i > qb) s1[i] = -1e30f;
      if (32 + kb + i > qb) s2[i] = -1e30f;
      if (48 + kb + i > qb) s3[i] = -1e30f;
    }
  }

  float pm = fmaxf(fmaxf(fmaxf(s0[0], s0[1]), fmaxf(s0[2], s0[3])),
                   fmaxf(fmaxf(s1[0], s1[1]), fmaxf(s1[2], s1[3])));
  pm = fmaxf(pm, fmaxf(fmaxf(fmaxf(s2[0], s2[1]), fmaxf(s2[2], s2[3])),
                       fmaxf(fmaxf(s3[0], s3[1]), fmaxf(s3[2], s3[3]))));
  pm = fmaxf(pm, __shfl_xor(pm, 16));
  pm = fmaxf(pm, __shfl_xor(pm, 32));

  const bool keep = __all(pm - m_i <= 8.f);
  const float mn = keep ? m_i : fmaxf(m_i, pm);
  const float sc = keep ? 1.f : __expf(m_i - mn);
  m_i = mn;
#pragma unroll
  for (int i = 0; i < 4; ++i) {
    s0[i] = __expf(s0[i] - mn);
    s1[i] = __expf(s1[i] - mn);
    s2[i] = __expf(s2[i] - mn);
    s3[i] = __expf(s3[i] - mn);
  }
  float rs = ((s0[0] + s0[1]) + (s0[2] + s0[3])) + ((s1[0] + s1[1]) + (s1[2] + s1[3]))
           + ((s2[0] + s2[1]) + (s2[2] + s2[3])) + ((s3[0] + s3[1]) + (s3[2] + s3[3]));
  rs += __shfl_xor(rs, 16);
  rs += __shfl_xor(rs, 32);
  if (keep) {
    l_i = l_i + rs;
  } else {
    l_i = l_i * sc + rs;
    o0 *= sc; o1 *= sc; o2 *= sc; o3 *= sc;
  }

  union { uint32_t u[4]; bf16x8 v; } B0, B1;
  B0.u[0] = cvt_pk(s0[0], s0[1]); B0.u[1] = cvt_pk(s0[2], s0[3]);
  B0.u[2] = cvt_pk(s1[0], s1[1]); B0.u[3] = cvt_pk(s1[2], s1[3]);
  B1.u[0] = cvt_pk(s2[0], s2[1]); B1.u[1] = cvt_pk(s2[2], s2[3]);
  B1.u[2] = cvt_pk(s3[0], s3[1]); B1.u[3] = cvt_pk(s3[2], s3[3]);

  o0 = __builtin_amdgcn_mfma_f32_16x16x32_bf16(vA0, B0.v, o0, 0, 0, 0);
  o0 = __builtin_amdgcn_mfma_f32_16x16x32_bf16(vB0, B1.v, o0, 0, 0, 0);
  o1 = __builtin_amdgcn_mfma_f32_16x16x32_bf16(vA1, B0.v, o1, 0, 0, 0);
  o1 = __builtin_amdgcn_mfma_f32_16x16x32_bf16(vB1, B1.v, o1, 0, 0, 0);
  o2 = __builtin_amdgcn_mfma_f32_16x16x32_bf16(vA2, B0.v, o2, 0, 0, 0);
  o2 = __builtin_amdgcn_mfma_f32_16x16x32_bf16(vB2, B1.v, o2, 0, 0, 0);
  o3 = __builtin_amdgcn_mfma_f32_16x16x32_bf16(vA3, B0.v, o3, 0, 0, 0);
  o3 = __builtin_amdgcn_mfma_f32_16x16x32_bf16(vB3, B1.v, o3, 0, 0, 0);
}

// ---------------- causal flash attention: 64 q-rows / wave ---------------
// grid 2048 x 64 threads. Wave owns q-rows [64s, 64s+64) as FOUR 16-row
// halves sharing ONE K set + ONE V set per k-tile (halves the L2
// line-request count vs 32-row waves -- the confirmed R17 lever).
// The k-loop carries `#pragma unroll 2`: exposes two independent k-tiles
// to the COMPILER scheduler so it can hoist iteration-2 loads above
// iteration-1 softmax/PV (the manual register-rotate version of this
// NaN'd 3x -- compiler-managed live ranges are the safe variant).
__global__ __launch_bounds__(64) void flash_attn(
    const bf16_t* __restrict__ Qg, const bf16_t* __restrict__ Kg,
    const bf16_t* __restrict__ VTg, bf16_t* __restrict__ Y)
{
  const int T = 2048, HS = 64;
  const int flat = blockIdx.x;         // 0..2047
  const int xcd = flat & 7;
  const int rest = flat >> 3;          // 0..255
  const int bh = xcd * 8 + (rest & 7); // 8 heads per XCD -> K/V L2-resident
  const int s = 31 - (rest >> 3);      // 64-row q-group, longest first
  const size_t baseQ = (size_t)bh * T * HS;   // Q,K: (bh, t, d)
  const size_t baseV = (size_t)bh * HS * T;   // V: (bh, kt, d, ksigma) tiles

  const int lane = threadIdx.x & 63;
  const int l15 = lane & 15, l4 = lane >> 4;

  const int bound = s;                 // last k-tile, same for all 4 halves
  const int kb = l4 * 4;
  const int qb0 = l15;
  const int qb1 = l15 + 16;
  const int qb2 = l15 + 32;
  const int qb3 = l15 + 48;

  const bf16_t* qr = Qg + baseQ + (size_t)(64 * s + l15) * HS;
  const bf16x8 aq00 = *(const bf16x8*)(qr + l4 * 8);
  const bf16x8 aq01 = *(const bf16x8*)(qr + 32 + l4 * 8);
  const bf16x8 aq10 = *(const bf16x8*)(qr + 16 * HS + l4 * 8);
  const bf16x8 aq11 = *(const bf16x8*)(qr + 16 * HS + 32 + l4 * 8);
  const bf16x8 aq20 = *(const bf16x8*)(qr + 32 * HS + l4 * 8);
  const bf16x8 aq21 = *(const bf16x8*)(qr + 32 * HS + 32 + l4 * 8);
  const bf16x8 aq30 = *(const bf16x8*)(qr + 48 * HS + l4 * 8);
  const bf16x8 aq31 = *(const bf16x8*)(qr + 48 * HS + 32 + l4 * 8);

  float m0 = -1e30f, l0 = 0.f, m1 = -1e30f, l1 = 0.f;
  float m2 = -1e30f, l2 = 0.f, m3 = -1e30f, l3 = 0.f;
  f32x4 o00 = {}, o01 = {}, o02 = {}, o03 = {};
  f32x4 o10 = {}, o11 = {}, o12 = {}, o13 = {};
  f32x4 o20 = {}, o21 = {}, o22 = {}, o23 = {};
  f32x4 o30 = {}, o31 = {}, o32 = {}, o33 = {};

  const bf16_t* kp = Kg + baseQ + (size_t)l15 * HS + l4 * 8;
  const bf16_t* vp = VTg + baseV + (size_t)l15 * 64 + l4 * 8;

#pragma unroll 2
  for (int kt = 0; kt <= bound; ++kt) {
    const bool dg = (kt == bound);
    const bf16x8 kA0 = *(const bf16x8*)(kp + 0);
    const bf16x8 kB0 = *(const bf16x8*)(kp + 32);
    const bf16x8 kA1 = *(const bf16x8*)(kp + 1024);
    const bf16x8 kB1 = *(const bf16x8*)(kp + 1024 + 32);
    const bf16x8 kA2 = *(const bf16x8*)(kp + 2048);
    const bf16x8 kB2 = *(const bf16x8*)(kp + 2048 + 32);
    const bf16x8 kA3 = *(const bf16x8*)(kp + 3072);
    const bf16x8 kB3 = *(const bf16x8*)(kp + 3072 + 32);
    const bf16x8 vA0 = *(const bf16x8*)(vp + 0);
    const bf16x8 vB0 = *(const bf16x8*)(vp + 32);
    const bf16x8 vA1 = *(const bf16x8*)(vp + 1024);
    const bf16x8 vB1 = *(const bf16x8*)(vp + 1024 + 32);
    const bf16x8 vA2 = *(const bf16x8*)(vp + 2048);
    const bf16x8 vB2 = *(const bf16x8*)(vp + 2048 + 32);
    const bf16x8 vA3 = *(const bf16x8*)(vp + 3072);
    const bf16x8 vB3 = *(const bf16x8*)(vp + 3072 + 32);

    half_step(kA0, kB0, kA1, kB1, kA2, kB2, kA3, kB3,
              vA0, vB0, vA1, vB1, vA2, vB2, vA3, vB3,
              aq00, aq01, m0, l0, o00, o01, o02, o03, dg, qb0, kb);
    half_step(kA0, kB0, kA1, kB1, kA2, kB2, kA3, kB3,
              vA0, vB0, vA1, vB1, vA2, vB2, vA3, vB3,
              aq10, aq11, m1, l1, o10, o11, o12, o13, dg, qb1, kb);
    half_step(kA0, kB0, kA1, kB1, kA2, kB2, kA3, kB3,
              vA0, vB0, vA1, vB1, vA2, vB2, vA3, vB3,
              aq20, aq21, m2, l2, o20, o21, o22, o23, dg, qb2, kb);
    half_step(kA0, kB0, kA1, kB1, kA2, kB2, kA3, kB3,
              vA0, vB0, vA1, vB1, vA2, vB2, vA3, vB3,
              aq30, aq31, m3, l3, o30, o31, o32, o33, dg, qb3, kb);

    kp += 4096;
    vp += 4096;
  }

  const int b = bh >> 4, h = bh & 15;
  {
    const float il = 1.f / l0;
    const int q = 64 * s + l15;
    bf16_t* yr = Y + ((size_t)(b * T + q)) * 1024 + h * 64 + l4 * 4;
    uint2 w;
    w.x = cvt_pk(o00[0] * il, o00[1] * il); w.y = cvt_pk(o00[2] * il, o00[3] * il);
    *(uint2*)(yr + 0) = w;
    w.x = cvt_pk(o01[0] * il, o01[1] * il); w.y = cvt_pk(o01[2] * il, o01[3] * il);
    *(uint2*)(yr + 16) = w;
    w.x = cvt_pk(o02[0] * il, o02[1] * il); w.y = cvt_pk(o02[2] * il, o02[3] * il);
    *(uint2*)(yr + 32) = w;
    w.x = cvt_pk(o03[0] * il, o03[1] * il); w.y = cvt_pk(o03[2] * il, o03[3] * il);
    *(uint2*)(yr + 48) = w;
  }
  {
    const float il = 1.f / l1;
    const int q = 64 * s + 16 + l15;
    bf16_t* yr = Y + ((size_t)(b * T + q)) * 1024 + h * 64 + l4 * 4;
    uint2 w;
    w.x = cvt_pk(o10[0] * il, o10[1] * il); w.y = cvt_pk(o10[2] * il, o10[3] * il);
    *(uint2*)(yr + 0) = w;
    w.x = cvt_pk(o11[0] * il, o11[1] * il); w.y = cvt_pk(o11[2] * il, o11[3] * il);
    *(uint2*)(yr + 16) = w;
    w.x = cvt_pk(o12[0] * il, o12[1] * il); w.y = cvt_pk(o12[2] * il, o12[3] * il);
    *(uint2*)(yr + 32) = w;
    w.x = cvt_pk(o13[0] * il, o13[1] * il); w.y = cvt_pk(o13[2] * il, o13[3] * il);
    *(uint2*)(yr + 48) = w;
  }
  {
    const float il = 1.f / l2;
    const int q = 64 * s + 32 + l15;
    bf16_t* yr = Y + ((size_t)(b * T + q)) * 1024 + h * 64 + l4 * 4;
    uint2 w;
    w.x = cvt_pk(o20[0] * il, o20[1] * il); w.y = cvt_pk(o20[2] * il, o20[3] * il);
    *(uint2*)(yr + 0) = w;
    w.x = cvt_pk(o21[0] * il, o21[1] * il); w.y = cvt_pk(o21[2] * il, o21[3] * il);
    *(uint2*)(yr + 16) = w;
    w.x = cvt_pk(o22[0] * il, o22[1] * il); w.y = cvt_pk(o22[2] * il, o22[3] * il);
    *(uint2*)(yr + 32) = w;
    w.x = cvt_pk(o23[0] * il, o23[1] * il); w.y = cvt_pk(o23[2] * il, o23[3] * il);
    *(uint2*)(yr + 48) = w;
  }
  {
    const float il = 1.f / l3;
    const int q = 64 * s + 48 + l15;
    bf16_t* yr = Y + ((size_t)(b * T + q)) * 1024 + h * 64 + l4 * 4;
    uint2 w;
    w.x = cvt_pk(o30[0] * il, o30[1] * il); w.y = cvt_pk(o30[2] * il, o30[3] * il);
    *(uint2*)(yr + 0) = w;
    w.x = cvt_pk(o31[0] * il, o31[1] * il); w.y = cvt_pk(o31[2] * il, o31[3] * il);
    *(uint2*)(yr + 16) = w;
    w.x = cvt_pk(o32[0] * il, o32[1] * il); w.y = cvt_pk(o32[2] * il, o32[3] * il);
    *(uint2*)(yr + 32) = w;
    w.x = cvt_pk(o33[0] * il, o33[1] * il); w.y = cvt_pk(o33[2] * il, o33[3] * il);
    *(uint2*)(yr + 48) = w;
  }
}

// ---------------- launch ----------------
extern "C" void kernel_launch(void* const* d_in, const int* in_sizes, int n_in,
                              void* d_out, int out_size, void* d_ws, size_t ws_size,
                              hipStream_t stream) {
  const float* x      = (const float*)d_in[0];
  const float* w_attn = (const float*)d_in[1];
  const float* b_attn = (const float*)d_in[2];
  const float* w_proj = (const float*)d_in[3];
  const float* b_proj = (const float*)d_in[4];
  float* out = (float*)d_out;

  char* ws = (char*)d_ws;
  bf16_t* xb   = (bf16_t*)(ws);
  bf16_t* wab  = (bf16_t*)(ws + 16777216);
  bf16_t* wpb  = (bf16_t*)(ws + 23068672);
  bf16_t* qkvb = (bf16_t*)(ws + 25165824);   // q | k | vTiles (8M elems each)
  bf16_t* yb   = (bf16_t*)(ws + 75497472);

  cvt_fused<<<2048, 256, 0, stream>>>(x, w_attn, w_proj, xb, wab, wpb);

  dim3 g1(24, 64);
  gemm_bt<0><<<g1, 256, 0, stream>>>(xb, wab, b_attn, (void*)qkvb, 8192, 3072, 1024);

  flash_attn<<<2048, 64, 0, stream>>>(qkvb, qkvb + 8388608, qkvb + 16777216, yb);

  dim3 g3(8, 64);
  gemm_bt<1><<<g3, 256, 0, stream>>>(yb, wpb, b_proj, (void*)out, 8192, 1024, 1024);
}